// Round 6
// baseline (96.246 us; speedup 1.0000x reference)
//
#include <hip/hip_runtime.h>
#include <math.h>

// Problem constants (fixed by reference: H=256, N=64, CH=1, L=2048)
#define NH   256
#define NN   64
#define LSEQ 2048
#define RS   72       // LDS row stride in bf16 elements (144 B: 16B-aligned rows)
#define PSZ  4608     // elems per 64-row component array (64*72), 9216 B
#define GSZ  2304     // elems per 32-row component array (32*72), 4608 B
#define NTH  1024

typedef __attribute__((ext_vector_type(8))) short short8;     // 8 bf16 (MFMA A/B frag)
typedef __attribute__((ext_vector_type(4))) float float4_t;   // 16x16 MFMA C/D frag
typedef __attribute__((ext_vector_type(16))) float float16_t; // 32x32 MFMA C/D frag
typedef unsigned short u16;

#define MFMA(a,b,c)   __builtin_amdgcn_mfma_f32_16x16x32_bf16((a),(b),(c),0,0,0)
#define MFMA32(a,b,c) __builtin_amdgcn_mfma_f32_32x32x16_bf16((a),(b),(c),0,0,0)
#define PERM_HI 0x07060302u   // [a.hi16 | b.hi16]

// DPP quad_perm: [1,0,3,2] = 177 (xor-1), [2,3,0,1] = 78 (xor-2)
#define QDPPU(v, ctrl) ((unsigned)__builtin_amdgcn_update_dpp(0, (int)(v), (ctrl), 0xf, 0xf, true))

// value v -> hi bits (bf16<<16) and lo bits (f32 of v-hi; its top16 = lo bf16)
static __device__ __forceinline__ void split2(float v, unsigned& hb, unsigned& lb) {
    hb = __float_as_uint(v) & 0xffff0000u;
    lb = __float_as_uint(v - __uint_as_float(hb));
}
// reconstruct f32 from separated hi/lo bf16 arrays
static __device__ __forceinline__ float ld2(const u16* hp, const u16* lp, int idx) {
    return __uint_as_float((unsigned)hp[idx] << 16)
         + __uint_as_float((unsigned)lp[idx] << 16);
}
static __device__ __forceinline__ short8 neg8(short8 v) {
    union { short8 s; int i[4]; } u; u.s = v;
#pragma unroll
    for (int m = 0; m < 4; ++m) u.i[m] ^= 0x80008000;
    return u.s;
}

// 4x4 transpose across 4 adjacent lanes (DPP quad_perm butterfly, VALU-only).
// In: reg i at lane j (j=lane&3) = M[i][j]. Out: reg i at lane j = M[j][i].
static __device__ __forceinline__ void quad_tr4(float* v, bool b0, bool b1) {
    unsigned u0 = __float_as_uint(v[0]), u1 = __float_as_uint(v[1]);
    unsigned u2 = __float_as_uint(v[2]), u3 = __float_as_uint(v[3]);
    unsigned t0 = QDPPU(u1, 177), t1 = QDPPU(u0, 177);
    unsigned t2 = QDPPU(u3, 177), t3 = QDPPU(u2, 177);
    u0 = b0 ? t0 : u0;
    u1 = b0 ? u1 : t1;
    u2 = b0 ? t2 : u2;
    u3 = b0 ? u3 : t3;
    t0 = QDPPU(u2, 78); t1 = QDPPU(u3, 78);
    t2 = QDPPU(u0, 78); t3 = QDPPU(u1, 78);
    u0 = b1 ? t0 : u0;
    u1 = b1 ? t1 : u1;
    u2 = b1 ? u2 : t2;
    u3 = b1 ? u3 : t3;
    v[0] = __uint_as_float(u0); v[1] = __uint_as_float(u1);
    v[2] = __uint_as_float(u2); v[3] = __uint_as_float(u3);
}

// quad-transpose pr/pi (4 consecutive output rows per lane), then store all 4
// planes (rh,rl,ih,il, SZ apart) as one b64 each at row = rowbase + (lane&3),
// cols colb..colb+3 (colb 4-aligned). Replaces 16 scalar b16 stores.
template<int SZ>
static __device__ __forceinline__ void tr_store4(
    u16* dst, int rowbase, int colb, int lane, float* pr, float* pi)
{
    quad_tr4(pr, lane & 1, lane & 2);
    quad_tr4(pi, lane & 1, lane & 2);
    unsigned hr[4], lr[4], hi[4], li[4];
#pragma unroll
    for (int rr = 0; rr < 4; ++rr) { split2(pr[rr], hr[rr], lr[rr]); split2(pi[rr], hi[rr], li[rr]); }
    const int rb = (rowbase + (lane & 3))*RS + colb;
    uint2 w;
    w.x = __builtin_amdgcn_perm(hr[1], hr[0], PERM_HI);
    w.y = __builtin_amdgcn_perm(hr[3], hr[2], PERM_HI);
    *(uint2*)&dst[rb] = w;
    w.x = __builtin_amdgcn_perm(lr[1], lr[0], PERM_HI);
    w.y = __builtin_amdgcn_perm(lr[3], lr[2], PERM_HI);
    *(uint2*)&dst[SZ + rb] = w;
    w.x = __builtin_amdgcn_perm(hi[1], hi[0], PERM_HI);
    w.y = __builtin_amdgcn_perm(hi[3], hi[2], PERM_HI);
    *(uint2*)&dst[2*SZ + rb] = w;
    w.x = __builtin_amdgcn_perm(li[1], li[0], PERM_HI);
    w.y = __builtin_amdgcn_perm(li[3], li[2], PERM_HI);
    *(uint2*)&dst[3*SZ + rb] = w;
}

// build hi/lo short8 frags from 8 f32 bit patterns (m1 global path only)
static __device__ __forceinline__ void frag_vals(const unsigned* e, short8& hi, short8& lo) {
    unsigned lb[8];
#pragma unroll
    for (int m = 0; m < 8; ++m) {
        unsigned hv = e[m] & 0xffff0000u;
        lb[m] = __float_as_uint(__uint_as_float(e[m]) - __uint_as_float(hv));
    }
    union { short8 s; unsigned u[4]; } H, L;
#pragma unroll
    for (int m = 0; m < 4; ++m) {
        H.u[m] = __builtin_amdgcn_perm(e[2*m+1],  e[2*m],  PERM_HI);
        L.u[m] = __builtin_amdgcn_perm(lb[2*m+1], lb[2*m], PERM_HI);
    }
    hi = H.s; lo = L.s;
}

// One 16x16 tile of complex P = A*B, K=64. A and B-transpose are separated
// hi/lo bf16 component arrays: [rh | rl | ih | il] each ASZ/BSZ elems apart.
template<int ASZ, int BSZ, bool IMAG>
static __device__ __forceinline__ void cmm_tile(
    const u16* __restrict__ Ab, const u16* __restrict__ Bb,
    int arow, int bcol, int fq,
    float4_t& accP, float4_t& accN, float4_t& accI1, float4_t& accI2)
{
#pragma unroll
    for (int ks = 0; ks < 2; ++ks) {
        const int k0 = ks*32 + fq*8;
        const u16* ap = Ab + arow*RS + k0;
        const u16* bp = Bb + bcol*RS + k0;
        short8 Arh = *(const short8*)(ap);
        short8 Arl = *(const short8*)(ap + ASZ);
        short8 Aih = *(const short8*)(ap + 2*ASZ);
        short8 Ail = *(const short8*)(ap + 3*ASZ);
        short8 Brh = *(const short8*)(bp);
        short8 Brl = *(const short8*)(bp + BSZ);
        short8 Bih = *(const short8*)(bp + 2*BSZ);
        short8 Bil = *(const short8*)(bp + 3*BSZ);
        accP = MFMA(Arh, Brh, accP); accP = MFMA(Arh, Brl, accP); accP = MFMA(Arl, Brh, accP);
        accN = MFMA(Aih, Bih, accN); accN = MFMA(Aih, Bil, accN); accN = MFMA(Ail, Bih, accN);
        if (IMAG) {
            accI1 = MFMA(Arh, Bih, accI1); accI1 = MFMA(Arh, Bil, accI1); accI1 = MFMA(Arl, Bih, accI1);
            accI2 = MFMA(Aih, Brh, accI2); accI2 = MFMA(Aih, Brl, accI2); accI2 = MFMA(Ail, Brh, accI2);
        }
    }
}

// Paired tiles: one A-row panel (arow), two B cols (bcol0, bcol0+16).
template<int ASZ, int BSZ>
static __device__ __forceinline__ void cmm_pair(
    const u16* __restrict__ Ab, const u16* __restrict__ Bb,
    int arow, int bcol0, int fq,
    float4_t& P0, float4_t& N0, float4_t& I10, float4_t& I20,
    float4_t& P1, float4_t& N1, float4_t& I11, float4_t& I21)
{
#pragma unroll
    for (int ks = 0; ks < 2; ++ks) {
        const int k0 = ks*32 + fq*8;
        const u16* ap = Ab + arow*RS + k0;
        short8 Arh = *(const short8*)(ap);
        short8 Arl = *(const short8*)(ap + ASZ);
        short8 Aih = *(const short8*)(ap + 2*ASZ);
        short8 Ail = *(const short8*)(ap + 3*ASZ);
        {
            const u16* bp0 = Bb + bcol0*RS + k0;
            short8 Brh = *(const short8*)(bp0);
            short8 Brl = *(const short8*)(bp0 + BSZ);
            short8 Bih = *(const short8*)(bp0 + 2*BSZ);
            short8 Bil = *(const short8*)(bp0 + 3*BSZ);
            P0 = MFMA(Arh, Brh, P0); P0 = MFMA(Arh, Brl, P0); P0 = MFMA(Arl, Brh, P0);
            N0 = MFMA(Aih, Bih, N0); N0 = MFMA(Aih, Bil, N0); N0 = MFMA(Ail, Bih, N0);
            I10 = MFMA(Arh, Bih, I10); I10 = MFMA(Arh, Bil, I10); I10 = MFMA(Arl, Bih, I10);
            I20 = MFMA(Aih, Brh, I20); I20 = MFMA(Aih, Brl, I20); I20 = MFMA(Ail, Brh, I20);
        }
        {
            const u16* bp1 = Bb + (bcol0 + 16)*RS + k0;
            short8 Brh = *(const short8*)(bp1);
            short8 Brl = *(const short8*)(bp1 + BSZ);
            short8 Bih = *(const short8*)(bp1 + 2*BSZ);
            short8 Bil = *(const short8*)(bp1 + 3*BSZ);
            P1 = MFMA(Arh, Brh, P1); P1 = MFMA(Arh, Brl, P1); P1 = MFMA(Arl, Brh, P1);
            N1 = MFMA(Aih, Bih, N1); N1 = MFMA(Aih, Bil, N1); N1 = MFMA(Ail, Bih, N1);
            I11 = MFMA(Arh, Bih, I11); I11 = MFMA(Arh, Bil, I11); I11 = MFMA(Arl, Bih, I11);
            I21 = MFMA(Aih, Brh, I21); I21 = MFMA(Aih, Brl, I21); I21 = MFMA(Ail, Brh, I21);
        }
    }
}

// 32x32 complex tile, K=64, via mfma_f32_32x32x16_bf16 (4 k-steps).
// TWO chains only (R, I): imag*imag folded via negated Aih/Ail (no spill).
template<int ASZ, int BSZ>
static __device__ __forceinline__ void cmm32_tile2(
    const u16* __restrict__ Ab, const u16* __restrict__ Bb,
    int arow, int bcol, int khalf,
    float16_t& R, float16_t& I)
{
#pragma unroll
    for (int ks = 0; ks < 4; ++ks) {
        const int k0 = ks*16 + khalf;
        const u16* ap = Ab + arow*RS + k0;
        const u16* bp = Bb + bcol*RS + k0;
        short8 Arh = *(const short8*)(ap);
        short8 Arl = *(const short8*)(ap + ASZ);
        short8 Aih = *(const short8*)(ap + 2*ASZ);
        short8 Ail = *(const short8*)(ap + 3*ASZ);
        short8 Brh = *(const short8*)(bp);
        short8 Brl = *(const short8*)(bp + BSZ);
        short8 Bih = *(const short8*)(bp + 2*BSZ);
        short8 Bil = *(const short8*)(bp + 3*BSZ);
        short8 nAih = neg8(Aih), nAil = neg8(Ail);
        R = MFMA32(Arh, Brh, R);  I = MFMA32(Arh, Bih, I);
        R = MFMA32(Arh, Brl, R);  I = MFMA32(Arh, Bil, I);
        R = MFMA32(Arl, Brh, R);  I = MFMA32(Arl, Bih, I);
        R = MFMA32(nAih, Bih, R); I = MFMA32(Aih, Brh, I);
        R = MFMA32(nAih, Bil, R); I = MFMA32(Aih, Brl, I);
        R = MFMA32(nAil, Bih, R); I = MFMA32(Ail, Brh, I);
    }
}

// store 16x16 C-frag into BOTH P views, all-b64: XT pre-transpose (4 rows per
// lane contiguous col-major), XR post-DPP-transpose (4 cols per lane).
static __device__ __forceinline__ void store_both16(
    u16* XR, u16* XT, int rowbase, int bcol, int colb, int lane,
    float* pr, float* pi)
{
    unsigned h0[4], l0[4], h1[4], l1[4];
#pragma unroll
    for (int rr = 0; rr < 4; ++rr) { split2(pr[rr], h0[rr], l0[rr]); split2(pi[rr], h1[rr], l1[rr]); }
    const int tb = bcol*RS + rowbase;
    uint2 w;
    w.x = __builtin_amdgcn_perm(h0[1], h0[0], PERM_HI);
    w.y = __builtin_amdgcn_perm(h0[3], h0[2], PERM_HI);
    *(uint2*)&XT[tb] = w;
    w.x = __builtin_amdgcn_perm(l0[1], l0[0], PERM_HI);
    w.y = __builtin_amdgcn_perm(l0[3], l0[2], PERM_HI);
    *(uint2*)&XT[PSZ + tb] = w;
    w.x = __builtin_amdgcn_perm(h1[1], h1[0], PERM_HI);
    w.y = __builtin_amdgcn_perm(h1[3], h1[2], PERM_HI);
    *(uint2*)&XT[2*PSZ + tb] = w;
    w.x = __builtin_amdgcn_perm(l1[1], l1[0], PERM_HI);
    w.y = __builtin_amdgcn_perm(l1[3], l1[2], PERM_HI);
    *(uint2*)&XT[3*PSZ + tb] = w;
    tr_store4<PSZ>(XR, rowbase, colb, lane, pr, pi);
}

// store 32x32 C-frag into BOTH views, all-b64 (per reg-quad: XT pre-transpose,
// XR post-transpose).
static __device__ __forceinline__ void store_P_vals32(
    u16* XR, u16* XT, int trow, int tcol, int lane,
    const float16_t& vR, const float16_t& vI)
{
    const int col  = tcol + (lane & 31);
    const int colb = tcol + (lane & 28);
    const int hi4  = (lane >> 5) * 4;
#pragma unroll
    for (int q = 0; q < 4; ++q) {
        float r4[4], i4[4];
#pragma unroll
        for (int rr = 0; rr < 4; ++rr) { r4[rr] = vR[4*q+rr]; i4[rr] = vI[4*q+rr]; }
        unsigned h0[4], l0[4], h1[4], l1[4];
#pragma unroll
        for (int rr = 0; rr < 4; ++rr) { split2(r4[rr], h0[rr], l0[rr]); split2(i4[rr], h1[rr], l1[rr]); }
        const int tb = col*RS + trow + 8*q + hi4;
        uint2 w;
        w.x = __builtin_amdgcn_perm(h0[1], h0[0], PERM_HI);
        w.y = __builtin_amdgcn_perm(h0[3], h0[2], PERM_HI);
        *(uint2*)&XT[tb] = w;
        w.x = __builtin_amdgcn_perm(l0[1], l0[0], PERM_HI);
        w.y = __builtin_amdgcn_perm(l0[3], l0[2], PERM_HI);
        *(uint2*)&XT[PSZ + tb] = w;
        w.x = __builtin_amdgcn_perm(h1[1], h1[0], PERM_HI);
        w.y = __builtin_amdgcn_perm(h1[3], h1[2], PERM_HI);
        *(uint2*)&XT[2*PSZ + tb] = w;
        w.x = __builtin_amdgcn_perm(l1[1], l1[0], PERM_HI);
        w.y = __builtin_amdgcn_perm(l1[3], l1[2], PERM_HI);
        *(uint2*)&XT[3*PSZ + tb] = w;
        tr_store4<PSZ>(XR, trow + 8*q + hi4, colb, lane, r4, i4);
    }
}

// k[h, 64j+i] = Re( g_j . x_i ),  g_j = c^T (dA^64)^j,  x_i = dA^i dB
// Cubic Newton: X1 = I + (dt/2)A; Y = Ab*X1; V = X1*Y; X2 = 3X1 - 3V + VY.
// P = dA = 2*X2 - I folded into m3 epilogue.
// dB = dt/2 (dA b + b): u = dA*b, then x0 = dt/2(u+b), x1 = dt/2(dA u + u).
// Ladder: 9 squarings to dA^512 on waves 0-3 (32x32 MFMA, 2-chain);
// riders run CONCURRENTLY on waves 8-15. All LDS stores b64 via DPP
// quad-transpose (round-5 post-mortem: scalar b16 stores were ~40% of the
// LDS-pipe slots).
__global__ __launch_bounds__(NTH, 4) void ssm_kernel(
    const float* __restrict__ Ag,
    const float* __restrict__ Bg,
    const float* __restrict__ Cg,
    const float* __restrict__ LogDt,
    float* __restrict__ outp)
{
    __shared__ __align__(16) unsigned char lds[130048];
    u16* XR = (u16*)(lds);            // P row-major: rh,rl,ih,il (4 x 9216 B)
    u16* XT = (u16*)(lds +  36864);   // P transposed: rh,rl,ih,il
    u16* XF = (u16*)(lds +  73728);   // Xf[v][q] = x_v[q]; aliased as U = Y^T in Newton
    u16* Gm = (u16*)(lds + 110592);   // G[j][q] = g_j[q], 32 rows (4 x 4608 B)
    float* bvr = (float*)(lds + 129024);
    float* bvi = (float*)(lds + 129280);
    float* urr = (float*)(lds + 129536);   // u = dA*b scratch
    float* uri = (float*)(lds + 129792);

    const int t    = threadIdx.x;
    const int lane = t & 63;
    const int wv   = t >> 6;                 // 0..15
    const int fm   = lane & 15, fq = lane >> 4;
    const int h    = blockIdx.x;

    // paired-tile mapping (waves 0-7): row band tip, col halves tjp*32 + {0,16}
    const int tip  = wv >> 1, tjp = wv & 1;
    const int parow = tip*16 + fm;
    const int pb0   = tjp*32 + fm;

    // 32x32 squaring mapping (waves 0-3): tile (ti2, tj2)
    const int ti2 = (wv >> 1) & 1, tj2 = wv & 1;
    const int arow32 = ti2*32 + (lane & 31);
    const int bcol32 = tj2*32 + (lane & 31);
    const int khalf  = (lane >> 5) * 8;

    const float dt  = expf(LogDt[h]);
    const float hdt = 0.5f * dt;

    const float2* A2 = (const float2*)(Ag + (size_t)h * NN * NN * 2);
    const float4_t z4 = {0.f, 0.f, 0.f, 0.f};

    // ---- seed P = X1 = I + (dt/2)A (both views, hi/lo); load b, c ----
#pragma unroll
    for (int e = 0; e < 4; ++e) {
        int idx = t + e*NTH;
        int i = idx >> 6, j = idx & 63;
        float2 a = A2[idx];
        unsigned hb, lb;
        split2((i == j ? 1.0f : 0.0f) + hdt * a.x, hb, lb);
        XR[i*RS + j]       = (u16)(hb >> 16);
        XR[PSZ + i*RS + j] = (u16)(lb >> 16);
        XT[j*RS + i]       = (u16)(hb >> 16);
        XT[PSZ + j*RS + i] = (u16)(lb >> 16);
        split2(hdt * a.y, hb, lb);
        XR[2*PSZ + i*RS + j] = (u16)(hb >> 16);
        XR[3*PSZ + i*RS + j] = (u16)(lb >> 16);
        XT[2*PSZ + j*RS + i] = (u16)(hb >> 16);
        XT[3*PSZ + j*RS + i] = (u16)(lb >> 16);
    }
    if (t < NN) {
        float2 bv = ((const float2*)Bg)[h*NN + t];
        float2 cv = ((const float2*)Cg)[h*NN + t];
        bvr[t] = bv.x; bvi[t] = bv.y;
        unsigned hb, lb;
        split2(cv.x, hb, lb);                 // g_0 = c
        Gm[t]       = (u16)(hb >> 16);
        Gm[GSZ + t] = (u16)(lb >> 16);
        split2(cv.y, hb, lb);
        Gm[2*GSZ + t] = (u16)(hb >> 16);
        Gm[3*GSZ + t] = (u16)(lb >> 16);
    }
    __syncthreads();

    // ---- m1: Y = Ab*X1 (Ab from global, Bt = XT); paired; Y^T -> XF (b32 pairs) ----
    if (wv < 8) {
        float4_t P0 = z4, N0 = z4, I10 = z4, I20 = z4;
        float4_t P1 = z4, N1 = z4, I11 = z4, I21 = z4;
#pragma unroll
        for (int ks = 0; ks < 2; ++ks) {
            const int k0 = ks*32 + fq*8;
            unsigned vr[8], vi[8];
#pragma unroll
            for (int j = 0; j < 8; ++j) {
                float2 a = A2[parow*NN + k0 + j];
                vr[j] = __float_as_uint((parow == k0 + j ? 1.0f : 0.0f) - hdt * a.x);
                vi[j] = __float_as_uint(-hdt * a.y);
            }
            short8 Arh, Arl, Aih, Ail;
            frag_vals(vr, Arh, Arl);
            frag_vals(vi, Aih, Ail);
#pragma unroll
            for (int p = 0; p < 2; ++p) {
                const u16* bp = XT + (pb0 + p*16)*RS + k0;
                short8 Brh = *(const short8*)(bp);
                short8 Brl = *(const short8*)(bp + PSZ);
                short8 Bih = *(const short8*)(bp + 2*PSZ);
                short8 Bil = *(const short8*)(bp + 3*PSZ);
                float4_t &aP = p ? P1 : P0, &aN = p ? N1 : N0;
                float4_t &aI1 = p ? I11 : I10, &aI2 = p ? I21 : I20;
                aP = MFMA(Arh, Brh, aP); aP = MFMA(Arh, Brl, aP); aP = MFMA(Arl, Brh, aP);
                aN = MFMA(Aih, Bih, aN); aN = MFMA(Aih, Bil, aN); aN = MFMA(Ail, Bih, aN);
                aI1 = MFMA(Arh, Bih, aI1); aI1 = MFMA(Arh, Bil, aI1); aI1 = MFMA(Arl, Bih, aI1);
                aI2 = MFMA(Aih, Brh, aI2); aI2 = MFMA(Aih, Brl, aI2); aI2 = MFMA(Ail, Brh, aI2);
            }
        }
#pragma unroll
        for (int p = 0; p < 2; ++p) {
            const int bcol = pb0 + p*16;
            const float4_t &aP = p ? P1 : P0, &aN = p ? N1 : N0;
            const float4_t &aI1 = p ? I11 : I10, &aI2 = p ? I21 : I20;
#pragma unroll
            for (int rp = 0; rp < 2; ++rp) {   // Y^T contiguous rows -> packed b32 pairs
                int row0 = tip*16 + fq*4 + rp*2;
                unsigned h0, l0, h1, l1;
                split2(aP[rp*2]   - aN[rp*2],   h0, l0);
                split2(aP[rp*2+1] - aN[rp*2+1], h1, l1);
                *(unsigned*)&XF[bcol*RS + row0]       = __builtin_amdgcn_perm(h1, h0, PERM_HI);
                *(unsigned*)&XF[PSZ + bcol*RS + row0] = __builtin_amdgcn_perm(l1, l0, PERM_HI);
                split2(aI1[rp*2]   + aI2[rp*2],   h0, l0);
                split2(aI1[rp*2+1] + aI2[rp*2+1], h1, l1);
                *(unsigned*)&XF[2*PSZ + bcol*RS + row0] = __builtin_amdgcn_perm(h1, h0, PERM_HI);
                *(unsigned*)&XF[3*PSZ + bcol*RS + row0] = __builtin_amdgcn_perm(l1, l0, PERM_HI);
            }
        }
    }
    __syncthreads();

    // ---- m2: V = X1*Y (A = XR, Bt = U = XF); paired; V -> XR (row view, b64) ----
    {
        float4_t P0 = z4, N0 = z4, I10 = z4, I20 = z4;
        float4_t P1 = z4, N1 = z4, I11 = z4, I21 = z4;
        if (wv < 8)
            cmm_pair<PSZ, PSZ>(XR, XF, parow, pb0, fq, P0, N0, I10, I20, P1, N1, I11, I21);
        __syncthreads();   // all X1/Y reads done
        if (wv < 8) {
#pragma unroll
            for (int p = 0; p < 2; ++p) {
                float pr[4], pi[4];
#pragma unroll
                for (int r = 0; r < 4; ++r) {
                    pr[r] = (p ? P1[r] : P0[r]) - (p ? N1[r] : N0[r]);
                    pi[r] = (p ? I11[r] : I10[r]) + (p ? I21[r] : I20[r]);
                }
                tr_store4<PSZ>(XR, tip*16 + fq*4, tjp*32 + p*16 + (fm & 12), lane, pr, pi);
            }
        }
    }
    __syncthreads();

    // ---- m3: P = dA = 2*(3X1 - 3V + V*Y) - I ; paired; write both views ----
    {
        float p_r[2][4], p_i[2][4];
        if (wv < 8) {
            float4_t P0 = z4, N0 = z4, I10 = z4, I20 = z4;
            float4_t P1 = z4, N1 = z4, I11 = z4, I21 = z4;
            cmm_pair<PSZ, PSZ>(XR, XF, parow, pb0, fq, P0, N0, I10, I20, P1, N1, I11, I21);
#pragma unroll
            for (int p = 0; p < 2; ++p) {
                const int bcol = pb0 + p*16;
                const float4_t &aP = p ? P1 : P0, &aN = p ? N1 : N0;
                const float4_t &aI1 = p ? I11 : I10, &aI2 = p ? I21 : I20;
#pragma unroll
                for (int r = 0; r < 4; ++r) {      // pre-barrier elementwise reads
                    int row = tip*16 + fq*4 + r;
                    float2 a = A2[row*NN + bcol];
                    float dd  = (row == bcol ? 1.0f : 0.0f);
                    float x1r = dd + hdt * a.x;
                    float x1i = hdt * a.y;
                    float vvr = ld2(XR, XR + PSZ, row*RS + bcol);
                    float vvi = ld2(XR + 2*PSZ, XR + 3*PSZ, row*RS + bcol);
                    p_r[p][r] = 2.0f*(3.0f*x1r - 3.0f*vvr + (aP[r] - aN[r])) - dd;
                    p_i[p][r] = 2.0f*(3.0f*x1i - 3.0f*vvi + (aI1[r] + aI2[r]));
                }
            }
        }
        __syncthreads();   // all V/Y reads done
        if (wv < 8) {
#pragma unroll
            for (int p = 0; p < 2; ++p)
                store_both16(XR, XT, tip*16 + fq*4, pb0 + p*16,
                             tjp*32 + p*16 + (fm & 12), lane, p_r[p], p_i[p]);
        }
    }
    __syncthreads();
    // P = dA (both views)

    // ---- u = dA*b (all 16 waves, 16 partials per row) ----
    {
        int n = t >> 4, part = t & 15;
        float ar = 0.f, ai = 0.f;
#pragma unroll
        for (int qq = 0; qq < 4; ++qq) {
            int k = part + 16*qq;
            float mr = ld2(XR, XR + PSZ, n*RS + k);
            float mi = ld2(XR + 2*PSZ, XR + 3*PSZ, n*RS + k);
            ar += mr*bvr[k] - mi*bvi[k];
            ai += mr*bvi[k] + mi*bvr[k];
        }
#pragma unroll
        for (int off = 8; off; off >>= 1) { ar += __shfl_xor(ar, off); ai += __shfl_xor(ai, off); }
        if (part == 0) { urr[n] = ar; uri[n] = ai; }
    }
    __syncthreads();

    // ---- ladder s = 1..9: riders (waves 8-15) CONCURRENT with 32x32 squaring (waves 0-3) ----
#pragma unroll 1
    for (int s = 1; s <= 9; ++s) {
        float16_t sR, sI;
        if (wv >= 8) {
            if (s == 1) {
                // x0 = h(u+b); x1 = h(dA u + u): 512 threads, 8 partials per row
                int n = (t >> 3) & 63, part = t & 7;
                float ar = 0.f, ai = 0.f;
#pragma unroll
                for (int qq = 0; qq < 8; ++qq) {
                    int k = part + 8*qq;
                    float mr = ld2(XR, XR + PSZ, n*RS + k);
                    float mi = ld2(XR + 2*PSZ, XR + 3*PSZ, n*RS + k);
                    ar += mr*urr[k] - mi*uri[k];
                    ai += mr*uri[k] + mi*urr[k];
                }
#pragma unroll
                for (int off = 4; off; off >>= 1) { ar += __shfl_xor(ar, off); ai += __shfl_xor(ai, off); }
                if (part == 0) {
                    float u_r = urr[n], u_i = uri[n];
                    unsigned hb, lb;
                    split2(hdt*(u_r + bvr[n]), hb, lb);
                    XF[n]       = (u16)(hb >> 16); XF[PSZ + n]       = (u16)(lb >> 16);
                    split2(hdt*(u_i + bvi[n]), hb, lb);
                    XF[2*PSZ + n] = (u16)(hb >> 16); XF[3*PSZ + n]   = (u16)(lb >> 16);
                    split2(hdt*(ar + u_r), hb, lb);
                    XF[RS + n]       = (u16)(hb >> 16); XF[PSZ + RS + n]   = (u16)(lb >> 16);
                    split2(hdt*(ai + u_i), hb, lb);
                    XF[2*PSZ + RS + n] = (u16)(hb >> 16); XF[3*PSZ + RS + n] = (u16)(lb >> 16);
                }
            } else if (s <= 6) {
                const int C = 1 << (s-1);
                const int w = wv - 8;
                const int nT = (s == 6) ? 8 : 4;
                if (w < nT) {
                    const int rt = w >> 2, ct = w & 3;
                    float4_t aP = z4, aN = z4, aI1 = z4, aI2 = z4;
                    cmm_tile<PSZ, PSZ, true>(XF, XR, rt*16 + fm, ct*16 + fm, fq, aP, aN, aI1, aI2);
                    float pr[4], pi[4];
#pragma unroll
                    for (int r = 0; r < 4; ++r) { pr[r] = aP[r] - aN[r]; pi[r] = aI1[r] + aI2[r]; }
                    tr_store4<PSZ>(XF, C + rt*16 + fq*4, ct*16 + (fm & 12), lane, pr, pi);
                }
            } else {
                const int C = 1 << (s-7);     // 1,2,4
                const int w = wv - 8;
                if (w < 4) {
                    float4_t aP = z4, aN = z4, aI1 = z4, aI2 = z4;
                    cmm_tile<GSZ, PSZ, true>(Gm, XT, fm, w*16 + fm, fq, aP, aN, aI1, aI2);
                    float pr[4], pi[4];
#pragma unroll
                    for (int r = 0; r < 4; ++r) { pr[r] = aP[r] - aN[r]; pi[r] = aI1[r] + aI2[r]; }
                    // rows C + fq*4 + (lane&3) <= 19 < 32: no mask
                    tr_store4<GSZ>(Gm, C + fq*4, w*16 + (fm & 12), lane, pr, pi);
                }
            }
        } else if (wv < 4) {
            // squaring (waves 0-3, 32x32 tiles, 2-chain): P <- P*P
#pragma unroll
            for (int g = 0; g < 16; ++g) { sR[g] = 0.f; sI[g] = 0.f; }
            cmm32_tile2<PSZ, PSZ>(XR, XT, arow32, bcol32, khalf, sR, sI);
        }
        __syncthreads();   // all P reads (riders + frags) complete
        if (wv < 4) {
            store_P_vals32(XR, XT, ti2*32, tj2*32, lane, sR, sI);
        }
        __syncthreads();
    }
    // P = dA^512 ; XF rows 0..63 = x_i ; Gm rows 0..7 = g_0..g_7

    // ---- tail tt = 0..3: chained dA^512 G-steps + K tiles (direct global) ----
    // G rows [8+8tt, 24+8tt) <- A rows [8tt, 8tt+16) (out row 8+ab+m depends
    // only on A row ab+m, so in-interval row overlap is benign).
#pragma unroll 1
    for (int tt = 0; tt < 4; ++tt) {
        if (tt < 3 && wv < 4) {
            const int ab = tt * 8;
            float4_t aP = z4, aN = z4, aI1 = z4, aI2 = z4;
            cmm_tile<GSZ, PSZ, true>(Gm, XT, ab + fm, wv*16 + fm, fq, aP, aN, aI1, aI2);
            float pr[4], pi[4];
#pragma unroll
            for (int r = 0; r < 4; ++r) { pr[r] = aP[r] - aN[r]; pi[r] = aI1[r] + aI2[r]; }
            quad_tr4(pr, lane & 1, lane & 2);
            quad_tr4(pi, lane & 1, lane & 2);
            const int row = 8 + ab + fq*4 + (lane & 3);
            if (row < 32) {
                const int colb = wv*16 + (fm & 12);
                unsigned hr[4], lr[4], hi[4], li[4];
#pragma unroll
                for (int rr = 0; rr < 4; ++rr) { split2(pr[rr], hr[rr], lr[rr]); split2(pi[rr], hi[rr], li[rr]); }
                const int rb = row*RS + colb;
                uint2 w;
                w.x = __builtin_amdgcn_perm(hr[1], hr[0], PERM_HI);
                w.y = __builtin_amdgcn_perm(hr[3], hr[2], PERM_HI);
                *(uint2*)&Gm[rb] = w;
                w.x = __builtin_amdgcn_perm(lr[1], lr[0], PERM_HI);
                w.y = __builtin_amdgcn_perm(lr[3], lr[2], PERM_HI);
                *(uint2*)&Gm[GSZ + rb] = w;
                w.x = __builtin_amdgcn_perm(hi[1], hi[0], PERM_HI);
                w.y = __builtin_amdgcn_perm(hi[3], hi[2], PERM_HI);
                *(uint2*)&Gm[2*GSZ + rb] = w;
                w.x = __builtin_amdgcn_perm(li[1], li[0], PERM_HI);
                w.y = __builtin_amdgcn_perm(li[3], li[2], PERM_HI);
                *(uint2*)&Gm[3*GSZ + rb] = w;
            }
        }
        if (wv >= 4 && wv < 8) {           // K rows [8tt, 8tt+8): float4 global store
            const int jb = tt * 8;
            // clamp A row inside Gm's 32 rows (rows >= 32 feed only discarded C rows)
            int ga = jb + fm; if (ga > 31) ga = 31;
            float4_t aP = z4, aN = z4, aI1 = z4, aI2 = z4;
            cmm_tile<GSZ, PSZ, false>(Gm, XF, ga, (wv-4)*16 + fm, fq, aP, aN, aI1, aI2);
            float pr[4];
#pragma unroll
            for (int r = 0; r < 4; ++r) pr[r] = aP[r] - aN[r];
            quad_tr4(pr, lane & 1, lane & 2);
            if (fq < 2) {
                const int row  = jb + fq*4 + (lane & 3);
                const int colb = (wv-4)*16 + (fm & 12);
                float4_t v; v[0] = pr[0]; v[1] = pr[1]; v[2] = pr[2]; v[3] = pr[3];
                *(float4_t*)&outp[(size_t)h * LSEQ + row*NN + colb] = v;
            }
        }
        if (tt < 3) __syncthreads();
    }
}

extern "C" void kernel_launch(void* const* d_in, const int* in_sizes, int n_in,
                              void* d_out, int out_size, void* d_ws, size_t ws_size,
                              hipStream_t stream) {
    const float* A  = (const float*)d_in[0];
    const float* B  = (const float*)d_in[1];
    const float* C  = (const float*)d_in[2];
    const float* ld = (const float*)d_in[3];
    float* out = (float*)d_out;
    ssm_kernel<<<dim3(NH), dim3(NTH), 0, stream>>>(A, B, C, ld, out);
}

// Round 7
// 94.955 us; speedup vs baseline: 1.0136x; 1.0136x over previous
//
#include <hip/hip_runtime.h>
#include <math.h>

// Problem constants (fixed by reference: H=256, N=64, CH=1, L=2048)
#define NH   256
#define NN   64
#define LSEQ 2048
#define RS   72       // LDS row stride in bf16 elements (144 B: 16B-aligned rows)
#define PSZ  4608     // elems per 64-row component array (64*72), 9216 B
#define GSZ  2304     // elems per 32-row component array (32*72), 4608 B
#define NTH  1024

typedef __attribute__((ext_vector_type(8))) short short8;     // 8 bf16 (MFMA A/B frag)
typedef __attribute__((ext_vector_type(4))) float float4_t;   // 16x16 MFMA C/D frag
typedef __attribute__((ext_vector_type(16))) float float16_t; // 32x32 MFMA C/D frag
typedef unsigned short u16;

#define MFMA(a,b,c)   __builtin_amdgcn_mfma_f32_16x16x32_bf16((a),(b),(c),0,0,0)
#define MFMA32(a,b,c) __builtin_amdgcn_mfma_f32_32x32x16_bf16((a),(b),(c),0,0,0)
#define PERM_HI 0x07060302u   // [a.hi16 | b.hi16]

// value v -> hi bits (bf16<<16) and lo bits (f32 of v-hi; its top16 = lo bf16)
static __device__ __forceinline__ void split2(float v, unsigned& hb, unsigned& lb) {
    hb = __float_as_uint(v) & 0xffff0000u;
    lb = __float_as_uint(v - __uint_as_float(hb));
}
// reconstruct f32 from separated hi/lo bf16 arrays
static __device__ __forceinline__ float ld2(const u16* hp, const u16* lp, int idx) {
    return __uint_as_float((unsigned)hp[idx] << 16)
         + __uint_as_float((unsigned)lp[idx] << 16);
}
static __device__ __forceinline__ short8 neg8(short8 v) {
    union { short8 s; int i[4]; } u; u.s = v;
#pragma unroll
    for (int m = 0; m < 4; ++m) u.i[m] ^= 0x80008000;
    return u.s;
}
// extract f32 value of element e (0/1) from packed-bf16 words hw/lw
static __device__ __forceinline__ float up2(unsigned hw, unsigned lw, int odd) {
    unsigned hb = odd ? (hw & 0xffff0000u) : (hw << 16);
    unsigned lb = odd ? (lw & 0xffff0000u) : (lw << 16);
    return __uint_as_float(hb) + __uint_as_float(lb);
}

// build hi/lo short8 frags from 8 f32 bit patterns (m1 global path only)
static __device__ __forceinline__ void frag_vals(const unsigned* e, short8& hi, short8& lo) {
    unsigned lb[8];
#pragma unroll
    for (int m = 0; m < 8; ++m) {
        unsigned hv = e[m] & 0xffff0000u;
        lb[m] = __float_as_uint(__uint_as_float(e[m]) - __uint_as_float(hv));
    }
    union { short8 s; unsigned u[4]; } H, L;
#pragma unroll
    for (int m = 0; m < 4; ++m) {
        H.u[m] = __builtin_amdgcn_perm(e[2*m+1],  e[2*m],  PERM_HI);
        L.u[m] = __builtin_amdgcn_perm(lb[2*m+1], lb[2*m], PERM_HI);
    }
    hi = H.s; lo = L.s;
}

// One 16x16 tile of complex P = A*B, K=64. A and B-transpose are separated
// hi/lo bf16 component arrays: [rh | rl | ih | il] each ASZ/BSZ elems apart.
template<int ASZ, int BSZ, bool IMAG>
static __device__ __forceinline__ void cmm_tile(
    const u16* __restrict__ Ab, const u16* __restrict__ Bb,
    int arow, int bcol, int fq,
    float4_t& accP, float4_t& accN, float4_t& accI1, float4_t& accI2)
{
#pragma unroll
    for (int ks = 0; ks < 2; ++ks) {
        const int k0 = ks*32 + fq*8;
        const u16* ap = Ab + arow*RS + k0;
        const u16* bp = Bb + bcol*RS + k0;
        short8 Arh = *(const short8*)(ap);
        short8 Arl = *(const short8*)(ap + ASZ);
        short8 Aih = *(const short8*)(ap + 2*ASZ);
        short8 Ail = *(const short8*)(ap + 3*ASZ);
        short8 Brh = *(const short8*)(bp);
        short8 Brl = *(const short8*)(bp + BSZ);
        short8 Bih = *(const short8*)(bp + 2*BSZ);
        short8 Bil = *(const short8*)(bp + 3*BSZ);
        accP = MFMA(Arh, Brh, accP); accP = MFMA(Arh, Brl, accP); accP = MFMA(Arl, Brh, accP);
        accN = MFMA(Aih, Bih, accN); accN = MFMA(Aih, Bil, accN); accN = MFMA(Ail, Bih, accN);
        if (IMAG) {
            accI1 = MFMA(Arh, Bih, accI1); accI1 = MFMA(Arh, Bil, accI1); accI1 = MFMA(Arl, Bih, accI1);
            accI2 = MFMA(Aih, Brh, accI2); accI2 = MFMA(Aih, Brl, accI2); accI2 = MFMA(Ail, Brh, accI2);
        }
    }
}

// Paired tiles: one A-row panel (arow), two B cols (bcol0, bcol0+16).
template<int ASZ, int BSZ>
static __device__ __forceinline__ void cmm_pair(
    const u16* __restrict__ Ab, const u16* __restrict__ Bb,
    int arow, int bcol0, int fq,
    float4_t& P0, float4_t& N0, float4_t& I10, float4_t& I20,
    float4_t& P1, float4_t& N1, float4_t& I11, float4_t& I21)
{
#pragma unroll
    for (int ks = 0; ks < 2; ++ks) {
        const int k0 = ks*32 + fq*8;
        const u16* ap = Ab + arow*RS + k0;
        short8 Arh = *(const short8*)(ap);
        short8 Arl = *(const short8*)(ap + ASZ);
        short8 Aih = *(const short8*)(ap + 2*ASZ);
        short8 Ail = *(const short8*)(ap + 3*ASZ);
        {
            const u16* bp0 = Bb + bcol0*RS + k0;
            short8 Brh = *(const short8*)(bp0);
            short8 Brl = *(const short8*)(bp0 + BSZ);
            short8 Bih = *(const short8*)(bp0 + 2*BSZ);
            short8 Bil = *(const short8*)(bp0 + 3*BSZ);
            P0 = MFMA(Arh, Brh, P0); P0 = MFMA(Arh, Brl, P0); P0 = MFMA(Arl, Brh, P0);
            N0 = MFMA(Aih, Bih, N0); N0 = MFMA(Aih, Bil, N0); N0 = MFMA(Ail, Bih, N0);
            I10 = MFMA(Arh, Bih, I10); I10 = MFMA(Arh, Bil, I10); I10 = MFMA(Arl, Bih, I10);
            I20 = MFMA(Aih, Brh, I20); I20 = MFMA(Aih, Brl, I20); I20 = MFMA(Ail, Brh, I20);
        }
        {
            const u16* bp1 = Bb + (bcol0 + 16)*RS + k0;
            short8 Brh = *(const short8*)(bp1);
            short8 Brl = *(const short8*)(bp1 + BSZ);
            short8 Bih = *(const short8*)(bp1 + 2*BSZ);
            short8 Bil = *(const short8*)(bp1 + 3*BSZ);
            P1 = MFMA(Arh, Brh, P1); P1 = MFMA(Arh, Brl, P1); P1 = MFMA(Arl, Brh, P1);
            N1 = MFMA(Aih, Bih, N1); N1 = MFMA(Aih, Bil, N1); N1 = MFMA(Ail, Bih, N1);
            I11 = MFMA(Arh, Bih, I11); I11 = MFMA(Arh, Bil, I11); I11 = MFMA(Arl, Bih, I11);
            I21 = MFMA(Aih, Brh, I21); I21 = MFMA(Aih, Brl, I21); I21 = MFMA(Ail, Brh, I21);
        }
    }
}

// 32x32 complex tile, K=64, via mfma_f32_32x32x16_bf16 (4 k-steps).
// TWO chains only (R, I): imag*imag folded via negated Aih/Ail (no spill).
template<int ASZ, int BSZ>
static __device__ __forceinline__ void cmm32_tile2(
    const u16* __restrict__ Ab, const u16* __restrict__ Bb,
    int arow, int bcol, int khalf,
    float16_t& R, float16_t& I)
{
#pragma unroll
    for (int ks = 0; ks < 4; ++ks) {
        const int k0 = ks*16 + khalf;
        const u16* ap = Ab + arow*RS + k0;
        const u16* bp = Bb + bcol*RS + k0;
        short8 Arh = *(const short8*)(ap);
        short8 Arl = *(const short8*)(ap + ASZ);
        short8 Aih = *(const short8*)(ap + 2*ASZ);
        short8 Ail = *(const short8*)(ap + 3*ASZ);
        short8 Brh = *(const short8*)(bp);
        short8 Brl = *(const short8*)(bp + BSZ);
        short8 Bih = *(const short8*)(bp + 2*BSZ);
        short8 Bil = *(const short8*)(bp + 3*BSZ);
        short8 nAih = neg8(Aih), nAil = neg8(Ail);
        R = MFMA32(Arh, Brh, R);  I = MFMA32(Arh, Bih, I);
        R = MFMA32(Arh, Brl, R);  I = MFMA32(Arh, Bil, I);
        R = MFMA32(Arl, Brh, R);  I = MFMA32(Arl, Bih, I);
        R = MFMA32(nAih, Bih, R); I = MFMA32(Aih, Brh, I);
        R = MFMA32(nAih, Bil, R); I = MFMA32(Aih, Brl, I);
        R = MFMA32(nAil, Bih, R); I = MFMA32(Ail, Brh, I);
    }
}

// store complex values p_r/p_i (16x16 C-frag rows) into BOTH P views.
static __device__ __forceinline__ void store_P_vals(
    u16* XR, u16* XT, int ti, int bcol, int fq,
    const float* p_r, const float* p_i)
{
    unsigned hR[4], lR[4], hI[4], lI[4];
#pragma unroll
    for (int r = 0; r < 4; ++r) {
        split2(p_r[r], hR[r], lR[r]);
        split2(p_i[r], hI[r], lI[r]);
        int row = ti*16 + fq*4 + r;
        XR[row*RS + bcol]         = (u16)(hR[r] >> 16);
        XR[PSZ + row*RS + bcol]   = (u16)(lR[r] >> 16);
        XR[2*PSZ + row*RS + bcol] = (u16)(hI[r] >> 16);
        XR[3*PSZ + row*RS + bcol] = (u16)(lI[r] >> 16);
    }
    int tb = bcol*RS + ti*16 + fq*4;
    uint2 w;
    w.x = __builtin_amdgcn_perm(hR[1], hR[0], PERM_HI);
    w.y = __builtin_amdgcn_perm(hR[3], hR[2], PERM_HI);
    *(uint2*)&XT[tb] = w;
    w.x = __builtin_amdgcn_perm(lR[1], lR[0], PERM_HI);
    w.y = __builtin_amdgcn_perm(lR[3], lR[2], PERM_HI);
    *(uint2*)&XT[PSZ + tb] = w;
    w.x = __builtin_amdgcn_perm(hI[1], hI[0], PERM_HI);
    w.y = __builtin_amdgcn_perm(hI[3], hI[2], PERM_HI);
    *(uint2*)&XT[2*PSZ + tb] = w;
    w.x = __builtin_amdgcn_perm(lI[1], lI[0], PERM_HI);
    w.y = __builtin_amdgcn_perm(lI[3], lI[2], PERM_HI);
    *(uint2*)&XT[3*PSZ + tb] = w;
}

// store 32x32 C-frag (16 regs: col=lane&31, row=(g&3)+8*(g>>2)+4*(lane>>5))
// into BOTH views. XR: scalar b16; XT: 4 consecutive rows per reg-quad -> b64.
static __device__ __forceinline__ void store_P_vals32(
    u16* XR, u16* XT, int trow, int tcol, int lane,
    const float16_t& vR, const float16_t& vI)
{
    const int col = tcol + (lane & 31);
    const int hi4 = (lane >> 5) * 4;
#pragma unroll
    for (int q = 0; q < 4; ++q) {
        unsigned hR[4], lR[4], hI[4], lI[4];
#pragma unroll
        for (int rr = 0; rr < 4; ++rr) {
            const int g = 4*q + rr;
            split2(vR[g], hR[rr], lR[rr]);
            split2(vI[g], hI[rr], lI[rr]);
            const int row = trow + rr + 8*q + hi4;
            XR[row*RS + col]         = (u16)(hR[rr] >> 16);
            XR[PSZ + row*RS + col]   = (u16)(lR[rr] >> 16);
            XR[2*PSZ + row*RS + col] = (u16)(hI[rr] >> 16);
            XR[3*PSZ + row*RS + col] = (u16)(lI[rr] >> 16);
        }
        const int tb = col*RS + trow + 8*q + hi4;   // 8B-aligned
        uint2 w;
        w.x = __builtin_amdgcn_perm(hR[1], hR[0], PERM_HI);
        w.y = __builtin_amdgcn_perm(hR[3], hR[2], PERM_HI);
        *(uint2*)&XT[tb] = w;
        w.x = __builtin_amdgcn_perm(lR[1], lR[0], PERM_HI);
        w.y = __builtin_amdgcn_perm(lR[3], lR[2], PERM_HI);
        *(uint2*)&XT[PSZ + tb] = w;
        w.x = __builtin_amdgcn_perm(hI[1], hI[0], PERM_HI);
        w.y = __builtin_amdgcn_perm(hI[3], hI[2], PERM_HI);
        *(uint2*)&XT[2*PSZ + tb] = w;
        w.x = __builtin_amdgcn_perm(lI[1], lI[0], PERM_HI);
        w.y = __builtin_amdgcn_perm(lI[3], lI[2], PERM_HI);
        *(uint2*)&XT[3*PSZ + tb] = w;
    }
}

// k[h, 64j+i] = Re( g_j . x_i ),  g_j = c^T (dA^64)^j,  x_i = dA^i dB
// Cubic Newton: X1 = I + (dt/2)A; Y = Ab*X1; V = X1*Y; X2 = 3X1 - 3V + VY.
// P = dA = 2*X2 - I folded into m3 epilogue.
// dB = dt/2 (dA b + b): u = dA*b, then x0 = dt/2(u+b), x1 = dt/2(dA u + u).
// Ladder: 9 squarings to dA^512 on waves 0-3 (32x32 MFMA, 2-chain, setprio);
// riders run CONCURRENTLY on waves 8-15. (Round-6 post-mortem: all pipes
// 20-35% busy -> latency-bound; DPP b64 stores regressed; reverted to the
// round-5 store scheme + setprio + vectorized u/s1 LDS reads.)
__global__ __launch_bounds__(NTH, 4) void ssm_kernel(
    const float* __restrict__ Ag,
    const float* __restrict__ Bg,
    const float* __restrict__ Cg,
    const float* __restrict__ LogDt,
    float* __restrict__ outp)
{
    __shared__ __align__(16) unsigned char lds[130048];
    u16* XR = (u16*)(lds);            // P row-major: rh,rl,ih,il (4 x 9216 B)
    u16* XT = (u16*)(lds +  36864);   // P transposed: rh,rl,ih,il
    u16* XF = (u16*)(lds +  73728);   // Xf[v][q] = x_v[q]; aliased as U = Y^T in Newton
    u16* Gm = (u16*)(lds + 110592);   // G[j][q] = g_j[q], 32 rows (4 x 4608 B)
    float* bvr = (float*)(lds + 129024);
    float* bvi = (float*)(lds + 129280);
    float* urr = (float*)(lds + 129536);   // u = dA*b scratch
    float* uri = (float*)(lds + 129792);

    const int t    = threadIdx.x;
    const int lane = t & 63;
    const int wv   = t >> 6;                 // 0..15
    const int fm   = lane & 15, fq = lane >> 4;
    const int h    = blockIdx.x;

    // paired-tile mapping (waves 0-7): row band tip, col halves tjp*32 + {0,16}
    const int tip  = wv >> 1, tjp = wv & 1;
    const int parow = tip*16 + fm;
    const int pb0   = tjp*32 + fm;
    const int pb1   = pb0 + 16;

    // 32x32 squaring mapping (waves 0-3): tile (ti2, tj2)
    const int ti2 = (wv >> 1) & 1, tj2 = wv & 1;
    const int arow32 = ti2*32 + (lane & 31);
    const int bcol32 = tj2*32 + (lane & 31);
    const int khalf  = (lane >> 5) * 8;

    const float dt  = expf(LogDt[h]);
    const float hdt = 0.5f * dt;

    const float2* A2 = (const float2*)(Ag + (size_t)h * NN * NN * 2);
    const float4_t z4 = {0.f, 0.f, 0.f, 0.f};

    // ---- seed P = X1 = I + (dt/2)A (both views, hi/lo); load b, c ----
#pragma unroll
    for (int e = 0; e < 4; ++e) {
        int idx = t + e*NTH;
        int i = idx >> 6, j = idx & 63;
        float2 a = A2[idx];
        unsigned hb, lb;
        split2((i == j ? 1.0f : 0.0f) + hdt * a.x, hb, lb);
        XR[i*RS + j]       = (u16)(hb >> 16);
        XR[PSZ + i*RS + j] = (u16)(lb >> 16);
        XT[j*RS + i]       = (u16)(hb >> 16);
        XT[PSZ + j*RS + i] = (u16)(lb >> 16);
        split2(hdt * a.y, hb, lb);
        XR[2*PSZ + i*RS + j] = (u16)(hb >> 16);
        XR[3*PSZ + i*RS + j] = (u16)(lb >> 16);
        XT[2*PSZ + j*RS + i] = (u16)(hb >> 16);
        XT[3*PSZ + j*RS + i] = (u16)(lb >> 16);
    }
    if (t < NN) {
        float2 bv = ((const float2*)Bg)[h*NN + t];
        float2 cv = ((const float2*)Cg)[h*NN + t];
        bvr[t] = bv.x; bvi[t] = bv.y;
        unsigned hb, lb;
        split2(cv.x, hb, lb);                 // g_0 = c
        Gm[t]       = (u16)(hb >> 16);
        Gm[GSZ + t] = (u16)(lb >> 16);
        split2(cv.y, hb, lb);
        Gm[2*GSZ + t] = (u16)(hb >> 16);
        Gm[3*GSZ + t] = (u16)(lb >> 16);
    }
    __syncthreads();

    // ---- m1: Y = Ab*X1 (Ab from global, Bt = XT); paired; Y^T -> XF (b32 pairs) ----
    if (wv < 8) {
        float4_t P0 = z4, N0 = z4, I10 = z4, I20 = z4;
        float4_t P1 = z4, N1 = z4, I11 = z4, I21 = z4;
#pragma unroll
        for (int ks = 0; ks < 2; ++ks) {
            const int k0 = ks*32 + fq*8;
            unsigned vr[8], vi[8];
#pragma unroll
            for (int j = 0; j < 8; ++j) {
                float2 a = A2[parow*NN + k0 + j];
                vr[j] = __float_as_uint((parow == k0 + j ? 1.0f : 0.0f) - hdt * a.x);
                vi[j] = __float_as_uint(-hdt * a.y);
            }
            short8 Arh, Arl, Aih, Ail;
            frag_vals(vr, Arh, Arl);
            frag_vals(vi, Aih, Ail);
#pragma unroll
            for (int p = 0; p < 2; ++p) {
                const u16* bp = XT + (pb0 + p*16)*RS + k0;
                short8 Brh = *(const short8*)(bp);
                short8 Brl = *(const short8*)(bp + PSZ);
                short8 Bih = *(const short8*)(bp + 2*PSZ);
                short8 Bil = *(const short8*)(bp + 3*PSZ);
                float4_t &aP = p ? P1 : P0, &aN = p ? N1 : N0;
                float4_t &aI1 = p ? I11 : I10, &aI2 = p ? I21 : I20;
                aP = MFMA(Arh, Brh, aP); aP = MFMA(Arh, Brl, aP); aP = MFMA(Arl, Brh, aP);
                aN = MFMA(Aih, Bih, aN); aN = MFMA(Aih, Bil, aN); aN = MFMA(Ail, Bih, aN);
                aI1 = MFMA(Arh, Bih, aI1); aI1 = MFMA(Arh, Bil, aI1); aI1 = MFMA(Arl, Bih, aI1);
                aI2 = MFMA(Aih, Brh, aI2); aI2 = MFMA(Aih, Brl, aI2); aI2 = MFMA(Ail, Brh, aI2);
            }
        }
#pragma unroll
        for (int p = 0; p < 2; ++p) {
            const int bcol = pb0 + p*16;
            const float4_t &aP = p ? P1 : P0, &aN = p ? N1 : N0;
            const float4_t &aI1 = p ? I11 : I10, &aI2 = p ? I21 : I20;
#pragma unroll
            for (int rp = 0; rp < 2; ++rp) {   // Y^T contiguous rows -> packed b32 pairs
                int row0 = tip*16 + fq*4 + rp*2;
                unsigned h0, l0, h1, l1;
                split2(aP[rp*2]   - aN[rp*2],   h0, l0);
                split2(aP[rp*2+1] - aN[rp*2+1], h1, l1);
                *(unsigned*)&XF[bcol*RS + row0]       = __builtin_amdgcn_perm(h1, h0, PERM_HI);
                *(unsigned*)&XF[PSZ + bcol*RS + row0] = __builtin_amdgcn_perm(l1, l0, PERM_HI);
                split2(aI1[rp*2]   + aI2[rp*2],   h0, l0);
                split2(aI1[rp*2+1] + aI2[rp*2+1], h1, l1);
                *(unsigned*)&XF[2*PSZ + bcol*RS + row0] = __builtin_amdgcn_perm(h1, h0, PERM_HI);
                *(unsigned*)&XF[3*PSZ + bcol*RS + row0] = __builtin_amdgcn_perm(l1, l0, PERM_HI);
            }
        }
    }
    __syncthreads();

    // ---- m2: V = X1*Y (A = XR, Bt = U = XF); paired; V -> XR (row view only) ----
    {
        float4_t P0 = z4, N0 = z4, I10 = z4, I20 = z4;
        float4_t P1 = z4, N1 = z4, I11 = z4, I21 = z4;
        if (wv < 8)
            cmm_pair<PSZ, PSZ>(XR, XF, parow, pb0, fq, P0, N0, I10, I20, P1, N1, I11, I21);
        __syncthreads();   // all X1/Y reads done
        if (wv < 8) {
#pragma unroll
            for (int p = 0; p < 2; ++p) {
                const int bcol = pb0 + p*16;
                const float4_t &aP = p ? P1 : P0, &aN = p ? N1 : N0;
                const float4_t &aI1 = p ? I11 : I10, &aI2 = p ? I21 : I20;
#pragma unroll
                for (int r = 0; r < 4; ++r) {
                    int row = tip*16 + fq*4 + r;
                    unsigned hb, lb;
                    split2(aP[r] - aN[r], hb, lb);
                    XR[row*RS + bcol]       = (u16)(hb >> 16);
                    XR[PSZ + row*RS + bcol] = (u16)(lb >> 16);
                    split2(aI1[r] + aI2[r], hb, lb);
                    XR[2*PSZ + row*RS + bcol] = (u16)(hb >> 16);
                    XR[3*PSZ + row*RS + bcol] = (u16)(lb >> 16);
                }
            }
        }
    }
    __syncthreads();

    // ---- m3: P = dA = 2*(3X1 - 3V + V*Y) - I ; paired; write both views ----
    {
        float p_r[2][4], p_i[2][4];
        if (wv < 8) {
            float4_t P0 = z4, N0 = z4, I10 = z4, I20 = z4;
            float4_t P1 = z4, N1 = z4, I11 = z4, I21 = z4;
            cmm_pair<PSZ, PSZ>(XR, XF, parow, pb0, fq, P0, N0, I10, I20, P1, N1, I11, I21);
#pragma unroll
            for (int p = 0; p < 2; ++p) {
                const int bcol = pb0 + p*16;
                const float4_t &aP = p ? P1 : P0, &aN = p ? N1 : N0;
                const float4_t &aI1 = p ? I11 : I10, &aI2 = p ? I21 : I20;
#pragma unroll
                for (int r = 0; r < 4; ++r) {      // pre-barrier elementwise reads
                    int row = tip*16 + fq*4 + r;
                    float2 a = A2[row*NN + bcol];
                    float dd  = (row == bcol ? 1.0f : 0.0f);
                    float x1r = dd + hdt * a.x;
                    float x1i = hdt * a.y;
                    float vvr = ld2(XR, XR + PSZ, row*RS + bcol);
                    float vvi = ld2(XR + 2*PSZ, XR + 3*PSZ, row*RS + bcol);
                    p_r[p][r] = 2.0f*(3.0f*x1r - 3.0f*vvr + (aP[r] - aN[r])) - dd;
                    p_i[p][r] = 2.0f*(3.0f*x1i - 3.0f*vvi + (aI1[r] + aI2[r]));
                }
            }
        }
        __syncthreads();   // all V/Y reads done
        if (wv < 8) {
            store_P_vals(XR, XT, tip, pb0, fq, p_r[0], p_i[0]);
            store_P_vals(XR, XT, tip, pb1, fq, p_r[1], p_i[1]);
        }
    }
    __syncthreads();
    // P = dA (both views)

    // ---- u = dA*b (all 16 waves; lane owns 4 consecutive k -> b64 reads) ----
    {
        int n = t >> 4, part = t & 15;
        const u16* bp = XR + n*RS + part*4;
        uint2 Hr = *(const uint2*)(bp);
        uint2 Lr = *(const uint2*)(bp + PSZ);
        uint2 Hi = *(const uint2*)(bp + 2*PSZ);
        uint2 Li = *(const uint2*)(bp + 3*PSZ);
        unsigned hr[2] = {Hr.x, Hr.y}, lr[2] = {Lr.x, Lr.y};
        unsigned hi_[2] = {Hi.x, Hi.y}, li_[2] = {Li.x, Li.y};
        float ar = 0.f, ai = 0.f;
#pragma unroll
        for (int e = 0; e < 4; ++e) {
            float mr = up2(hr[e>>1], lr[e>>1], e & 1);
            float mi = up2(hi_[e>>1], li_[e>>1], e & 1);
            int k = part*4 + e;
            ar += mr*bvr[k] - mi*bvi[k];
            ai += mr*bvi[k] + mi*bvr[k];
        }
#pragma unroll
        for (int off = 8; off; off >>= 1) { ar += __shfl_xor(ar, off); ai += __shfl_xor(ai, off); }
        if (part == 0) { urr[n] = ar; uri[n] = ai; }
    }
    __syncthreads();

    // ---- ladder s = 1..9: riders (waves 8-15) CONCURRENT with 32x32 squaring (waves 0-3) ----
#pragma unroll 1
    for (int s = 1; s <= 9; ++s) {
        float16_t sR, sI;
        if (wv >= 8) {
            if (s == 1) {
                // x0 = h(u+b); x1 = h(dA u + u): 512 threads; lane owns 8 consecutive k
                int n = (t >> 3) & 63, part = t & 7;
                const u16* bp = XR + n*RS + part*8;   // 16B-aligned (72 % 8 == 0)
                uint4 Hr = *(const uint4*)(bp);
                uint4 Lr = *(const uint4*)(bp + PSZ);
                uint4 Hi = *(const uint4*)(bp + 2*PSZ);
                uint4 Li = *(const uint4*)(bp + 3*PSZ);
                unsigned hr[4] = {Hr.x, Hr.y, Hr.z, Hr.w}, lr[4] = {Lr.x, Lr.y, Lr.z, Lr.w};
                unsigned hi_[4] = {Hi.x, Hi.y, Hi.z, Hi.w}, li_[4] = {Li.x, Li.y, Li.z, Li.w};
                float ar = 0.f, ai = 0.f;
#pragma unroll
                for (int e = 0; e < 8; ++e) {
                    float mr = up2(hr[e>>1], lr[e>>1], e & 1);
                    float mi = up2(hi_[e>>1], li_[e>>1], e & 1);
                    int k = part*8 + e;
                    ar += mr*urr[k] - mi*uri[k];
                    ai += mr*uri[k] + mi*urr[k];
                }
#pragma unroll
                for (int off = 4; off; off >>= 1) { ar += __shfl_xor(ar, off); ai += __shfl_xor(ai, off); }
                if (part == 0) {
                    float u_r = urr[n], u_i = uri[n];
                    unsigned hb, lb;
                    split2(hdt*(u_r + bvr[n]), hb, lb);
                    XF[n]       = (u16)(hb >> 16); XF[PSZ + n]       = (u16)(lb >> 16);
                    split2(hdt*(u_i + bvi[n]), hb, lb);
                    XF[2*PSZ + n] = (u16)(hb >> 16); XF[3*PSZ + n]   = (u16)(lb >> 16);
                    split2(hdt*(ar + u_r), hb, lb);
                    XF[RS + n]       = (u16)(hb >> 16); XF[PSZ + RS + n]   = (u16)(lb >> 16);
                    split2(hdt*(ai + u_i), hb, lb);
                    XF[2*PSZ + RS + n] = (u16)(hb >> 16); XF[3*PSZ + RS + n] = (u16)(lb >> 16);
                }
            } else if (s <= 6) {
                const int C = 1 << (s-1);
                const int w = wv - 8;
                const int nT = (s == 6) ? 8 : 4;
                if (w < nT) {
                    const int rt = w >> 2, ct = w & 3;
                    float4_t aP = z4, aN = z4, aI1 = z4, aI2 = z4;
                    cmm_tile<PSZ, PSZ, true>(XF, XR, rt*16 + fm, ct*16 + fm, fq, aP, aN, aI1, aI2);
#pragma unroll
                    for (int r = 0; r < 4; ++r) {
                        int orow = C + rt*16 + fq*4 + r;
                        int oc   = ct*16 + fm;
                        unsigned hb, lb;
                        split2(aP[r] - aN[r], hb, lb);
                        XF[orow*RS + oc]       = (u16)(hb >> 16);
                        XF[PSZ + orow*RS + oc] = (u16)(lb >> 16);
                        split2(aI1[r] + aI2[r], hb, lb);
                        XF[2*PSZ + orow*RS + oc] = (u16)(hb >> 16);
                        XF[3*PSZ + orow*RS + oc] = (u16)(lb >> 16);
                    }
                }
            } else {
                const int C = 1 << (s-7);     // 1,2,4
                const int w = wv - 8;
                if (w < 4) {
                    float4_t aP = z4, aN = z4, aI1 = z4, aI2 = z4;
                    cmm_tile<GSZ, PSZ, true>(Gm, XT, fm, w*16 + fm, fq, aP, aN, aI1, aI2);
#pragma unroll
                    for (int r = 0; r < 4; ++r) {
                        int orow = C + fq*4 + r;   // <= 19 < 32, no mask
                        int oc   = w*16 + fm;
                        unsigned hb, lb;
                        split2(aP[r] - aN[r], hb, lb);
                        Gm[orow*RS + oc]       = (u16)(hb >> 16);
                        Gm[GSZ + orow*RS + oc] = (u16)(lb >> 16);
                        split2(aI1[r] + aI2[r], hb, lb);
                        Gm[2*GSZ + orow*RS + oc] = (u16)(hb >> 16);
                        Gm[3*GSZ + orow*RS + oc] = (u16)(lb >> 16);
                    }
                }
            }
        } else if (wv < 4) {
            // squaring (waves 0-3, 32x32 tiles, 2-chain): P <- P*P
#pragma unroll
            for (int g = 0; g < 16; ++g) { sR[g] = 0.f; sI[g] = 0.f; }
            __builtin_amdgcn_s_setprio(1);   // T5: favor the long-pole MFMA waves
            cmm32_tile2<PSZ, PSZ>(XR, XT, arow32, bcol32, khalf, sR, sI);
            __builtin_amdgcn_s_setprio(0);
        }
        __syncthreads();   // all P reads (riders + frags) complete
        if (wv < 4) {
            store_P_vals32(XR, XT, ti2*32, tj2*32, lane, sR, sI);
        }
        __syncthreads();
    }
    // P = dA^512 ; XF rows 0..63 = x_i ; Gm rows 0..7 = g_0..g_7

    // ---- tail tt = 0..3: chained dA^512 G-steps + K tiles (direct global) ----
    // G rows [8+8tt, 24+8tt) <- A rows [8tt, 8tt+16) (out row 8+ab+m depends
    // only on A row ab+m, so in-interval row overlap is benign).
#pragma unroll 1
    for (int tt = 0; tt < 4; ++tt) {
        if (tt < 3 && wv < 4) {
            const int ab = tt * 8;
            float4_t aP = z4, aN = z4, aI1 = z4, aI2 = z4;
            cmm_tile<GSZ, PSZ, true>(Gm, XT, ab + fm, wv*16 + fm, fq, aP, aN, aI1, aI2);
#pragma unroll
            for (int r = 0; r < 4; ++r) {
                int orow = 8 + ab + fq*4 + r;
                if (orow < 32) {
                    int oc = wv*16 + fm;
                    unsigned hb, lb;
                    split2(aP[r] - aN[r], hb, lb);
                    Gm[orow*RS + oc]       = (u16)(hb >> 16);
                    Gm[GSZ + orow*RS + oc] = (u16)(lb >> 16);
                    split2(aI1[r] + aI2[r], hb, lb);
                    Gm[2*GSZ + orow*RS + oc] = (u16)(hb >> 16);
                    Gm[3*GSZ + orow*RS + oc] = (u16)(lb >> 16);
                }
            }
        }
        if (wv >= 4 && wv < 8) {           // K rows [8tt, 8tt+8): direct global store
            const int jb = tt * 8;
            // clamp A row inside Gm's 32 rows (rows >= 32 feed only discarded C rows)
            int ga = jb + fm; if (ga > 31) ga = 31;
            float4_t aP = z4, aN = z4, aI1 = z4, aI2 = z4;
            __builtin_amdgcn_s_setprio(1);
            cmm_tile<GSZ, PSZ, false>(Gm, XF, ga, (wv-4)*16 + fm, fq, aP, aN, aI1, aI2);
            __builtin_amdgcn_s_setprio(0);
            if (fq < 2) {
                size_t base = (size_t)h * LSEQ;
#pragma unroll
                for (int r = 0; r < 4; ++r)
                    outp[base + (jb + fq*4 + r)*NN + (wv-4)*16 + fm] = aP[r] - aN[r];
            }
        }
        if (tt < 3) __syncthreads();
    }
}

extern "C" void kernel_launch(void* const* d_in, const int* in_sizes, int n_in,
                              void* d_out, int out_size, void* d_ws, size_t ws_size,
                              hipStream_t stream) {
    const float* A  = (const float*)d_in[0];
    const float* B  = (const float*)d_in[1];
    const float* C  = (const float*)d_in[2];
    const float* ld = (const float*)d_in[3];
    float* out = (float*)d_out;
    ssm_kernel<<<dim3(NH), dim3(NTH), 0, stream>>>(A, B, C, ld, out);
}

// Round 8
// 93.353 us; speedup vs baseline: 1.0310x; 1.0172x over previous
//
#include <hip/hip_runtime.h>
#include <math.h>

// Problem constants (fixed by reference: H=256, N=64, CH=1, L=2048)
#define NH   256
#define NN   64
#define LSEQ 2048
#define RS   72       // u16 row stride for separated planes (144 B)
#define RSW  68       // u32 row stride for packed XR planes (272 B == 4 mod 32 banks)
#define PSZ  4608     // u16 elems per separated 64-row plane (64*72)
#define PSZW 4352     // u32 elems per packed 64-row plane (64*68)
#define GSZ  2304     // u16 elems per separated 32-row plane (32*72)
#define NTH  1024

typedef __attribute__((ext_vector_type(8))) short short8;     // 8 bf16 (MFMA A/B frag)
typedef __attribute__((ext_vector_type(4))) float float4_t;   // 16x16 MFMA C/D frag
typedef __attribute__((ext_vector_type(16))) float float16_t; // 32x32 MFMA C/D frag
typedef unsigned short u16;

#define MFMA(a,b,c)   __builtin_amdgcn_mfma_f32_16x16x32_bf16((a),(b),(c),0,0,0)
#define MFMA32(a,b,c) __builtin_amdgcn_mfma_f32_32x32x16_bf16((a),(b),(c),0,0,0)
#define PERM_HI 0x07060302u   // [a.hi16 | b.hi16]
#define PERM_LO 0x05040100u   // [a.lo16 | b.lo16]

// value v -> hi bits (bf16<<16) and lo bits (f32 of v-hi; top16 = lo bf16)
static __device__ __forceinline__ void split2(float v, unsigned& hb, unsigned& lb) {
    hb = __float_as_uint(v) & 0xffff0000u;
    lb = __float_as_uint(v - __uint_as_float(hb));
}
// packed word = [hi bf16 | lo bf16]
static __device__ __forceinline__ unsigned pack2(float v) {
    unsigned hb, lb; split2(v, hb, lb);
    return __builtin_amdgcn_perm(hb, lb, PERM_HI);
}
static __device__ __forceinline__ float unpack2(unsigned w) {
    return __uint_as_float(w & 0xffff0000u) + __uint_as_float(w << 16);
}
static __device__ __forceinline__ short8 neg8(short8 v) {
    union { short8 s; int i[4]; } u; u.s = v;
#pragma unroll
    for (int m = 0; m < 4; ++m) u.i[m] ^= 0x80008000;
    return u.s;
}

// hi/lo short8 frags from 8 packed words (2 uint4 loads + 8 v_perm)
static __device__ __forceinline__ void frag_packed(const unsigned* p, short8& hi, short8& lo) {
    const uint4* q = (const uint4*)p;
    uint4 d0 = q[0], d1 = q[1];
    unsigned e[8] = {d0.x, d0.y, d0.z, d0.w, d1.x, d1.y, d1.z, d1.w};
    union { short8 s; unsigned u[4]; } H, L;
#pragma unroll
    for (int m = 0; m < 4; ++m) {
        H.u[m] = __builtin_amdgcn_perm(e[2*m+1], e[2*m], PERM_HI);
        L.u[m] = __builtin_amdgcn_perm(e[2*m+1], e[2*m], PERM_LO);
    }
    hi = H.s; lo = L.s;
}

// hi/lo short8 frags from 8 f32 bit patterns (m1 global path only)
static __device__ __forceinline__ void frag_vals(const unsigned* e, short8& hi, short8& lo) {
    unsigned lb[8];
#pragma unroll
    for (int m = 0; m < 8; ++m) {
        unsigned hv = e[m] & 0xffff0000u;
        lb[m] = __float_as_uint(__uint_as_float(e[m]) - __uint_as_float(hv));
    }
    union { short8 s; unsigned u[4]; } H, L;
#pragma unroll
    for (int m = 0; m < 4; ++m) {
        H.u[m] = __builtin_amdgcn_perm(e[2*m+1],  e[2*m],  PERM_HI);
        L.u[m] = __builtin_amdgcn_perm(lb[2*m+1], lb[2*m], PERM_HI);
    }
    hi = H.s; lo = L.s;
}

// ---- cmm variants ----
// separated/separated (Gm x XT paths: s7-9 riders, tail)
template<int ASZ, int BSZ, bool IMAG>
static __device__ __forceinline__ void cmm_ss(
    const u16* __restrict__ Ab, const u16* __restrict__ Bb,
    int arow, int bcol, int fq,
    float4_t& accP, float4_t& accN, float4_t& accI1, float4_t& accI2)
{
#pragma unroll
    for (int ks = 0; ks < 2; ++ks) {
        const int k0 = ks*32 + fq*8;
        const u16* ap = Ab + arow*RS + k0;
        const u16* bp = Bb + bcol*RS + k0;
        short8 Arh = *(const short8*)(ap);
        short8 Arl = *(const short8*)(ap + ASZ);
        short8 Aih = *(const short8*)(ap + 2*ASZ);
        short8 Ail = *(const short8*)(ap + 3*ASZ);
        short8 Brh = *(const short8*)(bp);
        short8 Brl = *(const short8*)(bp + BSZ);
        short8 Bih = *(const short8*)(bp + 2*BSZ);
        short8 Bil = *(const short8*)(bp + 3*BSZ);
        accP = MFMA(Arh, Brh, accP); accP = MFMA(Arh, Brl, accP); accP = MFMA(Arl, Brh, accP);
        accN = MFMA(Aih, Bih, accN); accN = MFMA(Aih, Bil, accN); accN = MFMA(Ail, Bih, accN);
        if (IMAG) {
            accI1 = MFMA(Arh, Bih, accI1); accI1 = MFMA(Arh, Bil, accI1); accI1 = MFMA(Arl, Bih, accI1);
            accI2 = MFMA(Aih, Brh, accI2); accI2 = MFMA(Aih, Brl, accI2); accI2 = MFMA(Ail, Brh, accI2);
        }
    }
}

// A separated (XF) x B packed (XR) — X-round riders s2..6
template<int ASZ>
static __device__ __forceinline__ void cmm_spk(
    const u16* __restrict__ Ab, const unsigned* __restrict__ Bprl,
    const unsigned* __restrict__ BpiI,
    int arow, int bcol, int fq,
    float4_t& accP, float4_t& accN, float4_t& accI1, float4_t& accI2)
{
#pragma unroll
    for (int ks = 0; ks < 2; ++ks) {
        const int k0 = ks*32 + fq*8;
        const u16* ap = Ab + arow*RS + k0;
        short8 Arh = *(const short8*)(ap);
        short8 Arl = *(const short8*)(ap + ASZ);
        short8 Aih = *(const short8*)(ap + 2*ASZ);
        short8 Ail = *(const short8*)(ap + 3*ASZ);
        short8 Brh, Brl, Bih, Bil;
        frag_packed(Bprl + bcol*RSW + k0, Brh, Brl);
        frag_packed(BpiI + bcol*RSW + k0, Bih, Bil);
        accP = MFMA(Arh, Brh, accP); accP = MFMA(Arh, Brl, accP); accP = MFMA(Arl, Brh, accP);
        accN = MFMA(Aih, Bih, accN); accN = MFMA(Aih, Bil, accN); accN = MFMA(Ail, Bih, accN);
        accI1 = MFMA(Arh, Bih, accI1); accI1 = MFMA(Arh, Bil, accI1); accI1 = MFMA(Arl, Bih, accI1);
        accI2 = MFMA(Aih, Brh, accI2); accI2 = MFMA(Aih, Brl, accI2); accI2 = MFMA(Ail, Brh, accI2);
    }
}

// A packed (XR) x B separated (XF), paired B-cols — m2/m3
template<int BSZ>
static __device__ __forceinline__ void cmm_pair_pk(
    const unsigned* __restrict__ Aprl, const unsigned* __restrict__ ApiI,
    const u16* __restrict__ Bb,
    int arow, int bcol0, int fq,
    float4_t& P0, float4_t& N0, float4_t& I10, float4_t& I20,
    float4_t& P1, float4_t& N1, float4_t& I11, float4_t& I21)
{
#pragma unroll
    for (int ks = 0; ks < 2; ++ks) {
        const int k0 = ks*32 + fq*8;
        short8 Arh, Arl, Aih, Ail;
        frag_packed(Aprl + arow*RSW + k0, Arh, Arl);
        frag_packed(ApiI + arow*RSW + k0, Aih, Ail);
        {
            const u16* bp0 = Bb + bcol0*RS + k0;
            short8 Brh = *(const short8*)(bp0);
            short8 Brl = *(const short8*)(bp0 + BSZ);
            short8 Bih = *(const short8*)(bp0 + 2*BSZ);
            short8 Bil = *(const short8*)(bp0 + 3*BSZ);
            P0 = MFMA(Arh, Brh, P0); P0 = MFMA(Arh, Brl, P0); P0 = MFMA(Arl, Brh, P0);
            N0 = MFMA(Aih, Bih, N0); N0 = MFMA(Aih, Bil, N0); N0 = MFMA(Ail, Bih, N0);
            I10 = MFMA(Arh, Bih, I10); I10 = MFMA(Arh, Bil, I10); I10 = MFMA(Arl, Bih, I10);
            I20 = MFMA(Aih, Brh, I20); I20 = MFMA(Aih, Brl, I20); I20 = MFMA(Ail, Brh, I20);
        }
        {
            const u16* bp1 = Bb + (bcol0 + 16)*RS + k0;
            short8 Brh = *(const short8*)(bp1);
            short8 Brl = *(const short8*)(bp1 + BSZ);
            short8 Bih = *(const short8*)(bp1 + 2*BSZ);
            short8 Bil = *(const short8*)(bp1 + 3*BSZ);
            P1 = MFMA(Arh, Brh, P1); P1 = MFMA(Arh, Brl, P1); P1 = MFMA(Arl, Brh, P1);
            N1 = MFMA(Aih, Bih, N1); N1 = MFMA(Aih, Bil, N1); N1 = MFMA(Ail, Bih, N1);
            I11 = MFMA(Arh, Bih, I11); I11 = MFMA(Arh, Bil, I11); I11 = MFMA(Arl, Bih, I11);
            I21 = MFMA(Aih, Brh, I21); I21 = MFMA(Aih, Brl, I21); I21 = MFMA(Ail, Brh, I21);
        }
    }
}

// 32x32, A packed (XR) x B separated (XT), 2-chain — ladder squaring
template<int BSZ>
static __device__ __forceinline__ void cmm32_pk(
    const unsigned* __restrict__ Aprl, const unsigned* __restrict__ ApiI,
    const u16* __restrict__ Bb,
    int arow, int bcol, int khalf,
    float16_t& R, float16_t& I)
{
#pragma unroll
    for (int ks = 0; ks < 4; ++ks) {
        const int k0 = ks*16 + khalf;
        short8 Arh, Arl, Aih, Ail;
        frag_packed(Aprl + arow*RSW + k0, Arh, Arl);
        frag_packed(ApiI + arow*RSW + k0, Aih, Ail);
        const u16* bp = Bb + bcol*RS + k0;
        short8 Brh = *(const short8*)(bp);
        short8 Brl = *(const short8*)(bp + BSZ);
        short8 Bih = *(const short8*)(bp + 2*BSZ);
        short8 Bil = *(const short8*)(bp + 3*BSZ);
        short8 nAih = neg8(Aih), nAil = neg8(Ail);
        R = MFMA32(Arh, Brh, R);  I = MFMA32(Arh, Bih, I);
        R = MFMA32(Arh, Brl, R);  I = MFMA32(Arh, Bil, I);
        R = MFMA32(Arl, Brh, R);  I = MFMA32(Arl, Bih, I);
        R = MFMA32(nAih, Bih, R); I = MFMA32(Aih, Brh, I);
        R = MFMA32(nAih, Bil, R); I = MFMA32(Aih, Brl, I);
        R = MFMA32(nAil, Bih, R); I = MFMA32(Ail, Brh, I);
    }
}

// XT (transposed, separated planes) b64 store of 4 consecutive rows at one col
static __device__ __forceinline__ void store_XT16(
    u16* XT, int rowbase, int bcol, const float* p_r, const float* p_i)
{
    unsigned hR[4], lR[4], hI[4], lI[4];
#pragma unroll
    for (int r = 0; r < 4; ++r) { split2(p_r[r], hR[r], lR[r]); split2(p_i[r], hI[r], lI[r]); }
    int tb = bcol*RS + rowbase;
    uint2 w;
    w.x = __builtin_amdgcn_perm(hR[1], hR[0], PERM_HI);
    w.y = __builtin_amdgcn_perm(hR[3], hR[2], PERM_HI);
    *(uint2*)&XT[tb] = w;
    w.x = __builtin_amdgcn_perm(lR[1], lR[0], PERM_HI);
    w.y = __builtin_amdgcn_perm(lR[3], lR[2], PERM_HI);
    *(uint2*)&XT[PSZ + tb] = w;
    w.x = __builtin_amdgcn_perm(hI[1], hI[0], PERM_HI);
    w.y = __builtin_amdgcn_perm(hI[3], hI[2], PERM_HI);
    *(uint2*)&XT[2*PSZ + tb] = w;
    w.x = __builtin_amdgcn_perm(lI[1], lI[0], PERM_HI);
    w.y = __builtin_amdgcn_perm(lI[3], lI[2], PERM_HI);
    *(uint2*)&XT[3*PSZ + tb] = w;
}

// k[h, 64j+i] = Re( g_j . x_i ),  g_j = c^T (dA^64)^j,  x_i = dA^i dB
// Cubic Newton: X1 = I + (dt/2)A; Y = Ab*X1; V = X1*Y; X2 = 3X1 - 3V + VY.
// P = dA = 2*X2 - I folded into m3 epilogue.
// dB = dt/2 (dA b + b): u = dA*b, then x0 = dt/2(u+b), x1 = dt/2(dA u + u).
// Ladder: 9 squarings to dA^512 on waves 0-3 (32x32, 2-chain, setprio);
// riders concurrent on waves 8-15. XR row-view is PAIR-PACKED u32
// ([rh|rl],[ih|il]) so all XR stores are b32 (round-7 post-mortem: XR
// scalar-b16 stores were the largest LDS-slot block; reads keep the same
// instruction count, +8 v_perm per plane-pair on the idle VALU).
__global__ __launch_bounds__(NTH, 4) void ssm_kernel(
    const float* __restrict__ Ag,
    const float* __restrict__ Bg,
    const float* __restrict__ Cg,
    const float* __restrict__ LogDt,
    float* __restrict__ outp)
{
    __shared__ __align__(16) unsigned char lds[130048];
    unsigned* XRrl = (unsigned*)(lds);          // packed P rows [rh|rl] (17408 B)
    unsigned* XRiI = (unsigned*)(lds + 17408);  // packed P rows [ih|il]
    u16* XT = (u16*)(lds +  36864);   // P transposed: rh,rl,ih,il (4 x 9216 B)
    u16* XF = (u16*)(lds +  73728);   // Xf[v][q] = x_v[q]; aliased as U = Y^T in Newton
    u16* Gm = (u16*)(lds + 110592);   // G[j][q] = g_j[q], 32 rows (4 x 4608 B)
    float* bvr = (float*)(lds + 129024);
    float* bvi = (float*)(lds + 129280);
    float* urr = (float*)(lds + 129536);   // u = dA*b scratch
    float* uri = (float*)(lds + 129792);

    const int t    = threadIdx.x;
    const int lane = t & 63;
    const int wv   = t >> 6;                 // 0..15
    const int fm   = lane & 15, fq = lane >> 4;
    const int h    = blockIdx.x;

    // paired-tile mapping (waves 0-7): row band tip, col halves tjp*32 + {0,16}
    const int tip  = wv >> 1, tjp = wv & 1;
    const int parow = tip*16 + fm;
    const int pb0   = tjp*32 + fm;
    const int pb1   = pb0 + 16;

    // 32x32 squaring mapping (waves 0-3): tile (ti2, tj2)
    const int ti2 = (wv >> 1) & 1, tj2 = wv & 1;
    const int arow32 = ti2*32 + (lane & 31);
    const int bcol32 = tj2*32 + (lane & 31);
    const int khalf  = (lane >> 5) * 8;

    const float dt  = expf(LogDt[h]);
    const float hdt = 0.5f * dt;

    const float2* A2 = (const float2*)(Ag + (size_t)h * NN * NN * 2);
    const float4_t z4 = {0.f, 0.f, 0.f, 0.f};

    // ---- seed P = X1 = I + (dt/2)A (both views); load b, c ----
#pragma unroll
    for (int e = 0; e < 4; ++e) {
        int idx = t + e*NTH;
        int i = idx >> 6, j = idx & 63;
        float2 a = A2[idx];
        float x1r = (i == j ? 1.0f : 0.0f) + hdt * a.x;
        float x1i = hdt * a.y;
        XRrl[i*RSW + j] = pack2(x1r);
        XRiI[i*RSW + j] = pack2(x1i);
        unsigned hb, lb;
        split2(x1r, hb, lb);
        XT[j*RS + i]       = (u16)(hb >> 16);
        XT[PSZ + j*RS + i] = (u16)(lb >> 16);
        split2(x1i, hb, lb);
        XT[2*PSZ + j*RS + i] = (u16)(hb >> 16);
        XT[3*PSZ + j*RS + i] = (u16)(lb >> 16);
    }
    if (t < NN) {
        float2 bv = ((const float2*)Bg)[h*NN + t];
        float2 cv = ((const float2*)Cg)[h*NN + t];
        bvr[t] = bv.x; bvi[t] = bv.y;
        unsigned hb, lb;
        split2(cv.x, hb, lb);                 // g_0 = c
        Gm[t]       = (u16)(hb >> 16);
        Gm[GSZ + t] = (u16)(lb >> 16);
        split2(cv.y, hb, lb);
        Gm[2*GSZ + t] = (u16)(hb >> 16);
        Gm[3*GSZ + t] = (u16)(lb >> 16);
    }
    __syncthreads();

    // ---- m1: Y = Ab*X1 (Ab from global, Bt = XT); paired; Y^T -> XF (b32 pairs) ----
    if (wv < 8) {
        float4_t P0 = z4, N0 = z4, I10 = z4, I20 = z4;
        float4_t P1 = z4, N1 = z4, I11 = z4, I21 = z4;
#pragma unroll
        for (int ks = 0; ks < 2; ++ks) {
            const int k0 = ks*32 + fq*8;
            unsigned vr[8], vi[8];
#pragma unroll
            for (int j = 0; j < 8; ++j) {
                float2 a = A2[parow*NN + k0 + j];
                vr[j] = __float_as_uint((parow == k0 + j ? 1.0f : 0.0f) - hdt * a.x);
                vi[j] = __float_as_uint(-hdt * a.y);
            }
            short8 Arh, Arl, Aih, Ail;
            frag_vals(vr, Arh, Arl);
            frag_vals(vi, Aih, Ail);
#pragma unroll
            for (int p = 0; p < 2; ++p) {
                const u16* bp = XT + (pb0 + p*16)*RS + k0;
                short8 Brh = *(const short8*)(bp);
                short8 Brl = *(const short8*)(bp + PSZ);
                short8 Bih = *(const short8*)(bp + 2*PSZ);
                short8 Bil = *(const short8*)(bp + 3*PSZ);
                float4_t &aP = p ? P1 : P0, &aN = p ? N1 : N0;
                float4_t &aI1 = p ? I11 : I10, &aI2 = p ? I21 : I20;
                aP = MFMA(Arh, Brh, aP); aP = MFMA(Arh, Brl, aP); aP = MFMA(Arl, Brh, aP);
                aN = MFMA(Aih, Bih, aN); aN = MFMA(Aih, Bil, aN); aN = MFMA(Ail, Bih, aN);
                aI1 = MFMA(Arh, Bih, aI1); aI1 = MFMA(Arh, Bil, aI1); aI1 = MFMA(Arl, Bih, aI1);
                aI2 = MFMA(Aih, Brh, aI2); aI2 = MFMA(Aih, Brl, aI2); aI2 = MFMA(Ail, Brh, aI2);
            }
        }
#pragma unroll
        for (int p = 0; p < 2; ++p) {
            const int bcol = pb0 + p*16;
            const float4_t &aP = p ? P1 : P0, &aN = p ? N1 : N0;
            const float4_t &aI1 = p ? I11 : I10, &aI2 = p ? I21 : I20;
#pragma unroll
            for (int rp = 0; rp < 2; ++rp) {   // Y^T contiguous rows -> packed b32 pairs
                int row0 = tip*16 + fq*4 + rp*2;
                unsigned h0, l0, h1, l1;
                split2(aP[rp*2]   - aN[rp*2],   h0, l0);
                split2(aP[rp*2+1] - aN[rp*2+1], h1, l1);
                *(unsigned*)&XF[bcol*RS + row0]       = __builtin_amdgcn_perm(h1, h0, PERM_HI);
                *(unsigned*)&XF[PSZ + bcol*RS + row0] = __builtin_amdgcn_perm(l1, l0, PERM_HI);
                split2(aI1[rp*2]   + aI2[rp*2],   h0, l0);
                split2(aI1[rp*2+1] + aI2[rp*2+1], h1, l1);
                *(unsigned*)&XF[2*PSZ + bcol*RS + row0] = __builtin_amdgcn_perm(h1, h0, PERM_HI);
                *(unsigned*)&XF[3*PSZ + bcol*RS + row0] = __builtin_amdgcn_perm(l1, l0, PERM_HI);
            }
        }
    }
    __syncthreads();

    // ---- m2: V = X1*Y (A = XR packed, Bt = U = XF); paired; V -> XR (b32) ----
    {
        float4_t P0 = z4, N0 = z4, I10 = z4, I20 = z4;
        float4_t P1 = z4, N1 = z4, I11 = z4, I21 = z4;
        if (wv < 8)
            cmm_pair_pk<PSZ>(XRrl, XRiI, XF, parow, pb0, fq, P0, N0, I10, I20, P1, N1, I11, I21);
        __syncthreads();   // all X1/Y reads done
        if (wv < 8) {
#pragma unroll
            for (int p = 0; p < 2; ++p) {
                const int bcol = pb0 + p*16;
#pragma unroll
                for (int r = 0; r < 4; ++r) {
                    int row = tip*16 + fq*4 + r;
                    float vr = (p ? P1[r] : P0[r]) - (p ? N1[r] : N0[r]);
                    float vi = (p ? I11[r] : I10[r]) + (p ? I21[r] : I20[r]);
                    XRrl[row*RSW + bcol] = pack2(vr);
                    XRiI[row*RSW + bcol] = pack2(vi);
                }
            }
        }
    }
    __syncthreads();

    // ---- m3: P = dA = 2*(3X1 - 3V + V*Y) - I ; paired; write both views ----
    {
        float p_r[2][4], p_i[2][4];
        if (wv < 8) {
            float4_t P0 = z4, N0 = z4, I10 = z4, I20 = z4;
            float4_t P1 = z4, N1 = z4, I11 = z4, I21 = z4;
            cmm_pair_pk<PSZ>(XRrl, XRiI, XF, parow, pb0, fq, P0, N0, I10, I20, P1, N1, I11, I21);
#pragma unroll
            for (int p = 0; p < 2; ++p) {
                const int bcol = pb0 + p*16;
                const float4_t &aP = p ? P1 : P0, &aN = p ? N1 : N0;
                const float4_t &aI1 = p ? I11 : I10, &aI2 = p ? I21 : I20;
#pragma unroll
                for (int r = 0; r < 4; ++r) {      // pre-barrier elementwise reads
                    int row = tip*16 + fq*4 + r;
                    float2 a = A2[row*NN + bcol];
                    float dd  = (row == bcol ? 1.0f : 0.0f);
                    float x1r = dd + hdt * a.x;
                    float x1i = hdt * a.y;
                    float vvr = unpack2(XRrl[row*RSW + bcol]);
                    float vvi = unpack2(XRiI[row*RSW + bcol]);
                    p_r[p][r] = 2.0f*(3.0f*x1r - 3.0f*vvr + (aP[r] - aN[r])) - dd;
                    p_i[p][r] = 2.0f*(3.0f*x1i - 3.0f*vvi + (aI1[r] + aI2[r]));
                }
            }
        }
        __syncthreads();   // all V/Y reads done
        if (wv < 8) {
#pragma unroll
            for (int p = 0; p < 2; ++p) {
                const int bcol = pb0 + p*16;
#pragma unroll
                for (int r = 0; r < 4; ++r) {
                    int row = tip*16 + fq*4 + r;
                    XRrl[row*RSW + bcol] = pack2(p_r[p][r]);
                    XRiI[row*RSW + bcol] = pack2(p_i[p][r]);
                }
                store_XT16(XT, tip*16 + fq*4, bcol, p_r[p], p_i[p]);
            }
        }
    }
    __syncthreads();
    // P = dA (both views)

    // ---- u = dA*b (all 16 waves; lane owns 4 consecutive k -> uint4 reads) ----
    {
        int n = t >> 4, part = t & 15;
        uint4 Wr = *(const uint4*)(XRrl + n*RSW + part*4);
        uint4 Wi = *(const uint4*)(XRiI + n*RSW + part*4);
        unsigned wr[4] = {Wr.x, Wr.y, Wr.z, Wr.w};
        unsigned wi[4] = {Wi.x, Wi.y, Wi.z, Wi.w};
        float ar = 0.f, ai = 0.f;
#pragma unroll
        for (int e = 0; e < 4; ++e) {
            float mr = unpack2(wr[e]);
            float mi = unpack2(wi[e]);
            int k = part*4 + e;
            ar += mr*bvr[k] - mi*bvi[k];
            ai += mr*bvi[k] + mi*bvr[k];
        }
#pragma unroll
        for (int off = 8; off; off >>= 1) { ar += __shfl_xor(ar, off); ai += __shfl_xor(ai, off); }
        if (part == 0) { urr[n] = ar; uri[n] = ai; }
    }
    __syncthreads();

    // ---- ladder s = 1..9: riders (waves 8-15) CONCURRENT with 32x32 squaring (waves 0-3) ----
#pragma unroll 1
    for (int s = 1; s <= 9; ++s) {
        float16_t sR, sI;
        if (wv >= 8) {
            if (s == 1) {
                // x0 = h(u+b); x1 = h(dA u + u): 512 threads; lane owns 8 consecutive k
                int n = (t >> 3) & 63, part = t & 7;
                const unsigned* rp0 = XRrl + n*RSW + part*8;
                const unsigned* ip0 = XRiI + n*RSW + part*8;
                uint4 Wr0 = *(const uint4*)(rp0), Wr1 = *(const uint4*)(rp0 + 4);
                uint4 Wi0 = *(const uint4*)(ip0), Wi1 = *(const uint4*)(ip0 + 4);
                unsigned wr[8] = {Wr0.x, Wr0.y, Wr0.z, Wr0.w, Wr1.x, Wr1.y, Wr1.z, Wr1.w};
                unsigned wi[8] = {Wi0.x, Wi0.y, Wi0.z, Wi0.w, Wi1.x, Wi1.y, Wi1.z, Wi1.w};
                float ar = 0.f, ai = 0.f;
#pragma unroll
                for (int e = 0; e < 8; ++e) {
                    float mr = unpack2(wr[e]);
                    float mi = unpack2(wi[e]);
                    int k = part*8 + e;
                    ar += mr*urr[k] - mi*uri[k];
                    ai += mr*uri[k] + mi*urr[k];
                }
#pragma unroll
                for (int off = 4; off; off >>= 1) { ar += __shfl_xor(ar, off); ai += __shfl_xor(ai, off); }
                if (part == 0) {
                    float u_r = urr[n], u_i = uri[n];
                    unsigned hb, lb;
                    split2(hdt*(u_r + bvr[n]), hb, lb);
                    XF[n]       = (u16)(hb >> 16); XF[PSZ + n]       = (u16)(lb >> 16);
                    split2(hdt*(u_i + bvi[n]), hb, lb);
                    XF[2*PSZ + n] = (u16)(hb >> 16); XF[3*PSZ + n]   = (u16)(lb >> 16);
                    split2(hdt*(ar + u_r), hb, lb);
                    XF[RS + n]       = (u16)(hb >> 16); XF[PSZ + RS + n]   = (u16)(lb >> 16);
                    split2(hdt*(ai + u_i), hb, lb);
                    XF[2*PSZ + RS + n] = (u16)(hb >> 16); XF[3*PSZ + RS + n] = (u16)(lb >> 16);
                }
            } else if (s <= 6) {
                const int C = 1 << (s-1);
                const int w = wv - 8;
                const int nT = (s == 6) ? 8 : 4;
                if (w < nT) {
                    const int rt = w >> 2, ct = w & 3;
                    float4_t aP = z4, aN = z4, aI1 = z4, aI2 = z4;
                    cmm_spk<PSZ>(XF, XRrl, XRiI, rt*16 + fm, ct*16 + fm, fq, aP, aN, aI1, aI2);
#pragma unroll
                    for (int r = 0; r < 4; ++r) {
                        int orow = C + rt*16 + fq*4 + r;
                        int oc   = ct*16 + fm;
                        unsigned hb, lb;
                        split2(aP[r] - aN[r], hb, lb);
                        XF[orow*RS + oc]       = (u16)(hb >> 16);
                        XF[PSZ + orow*RS + oc] = (u16)(lb >> 16);
                        split2(aI1[r] + aI2[r], hb, lb);
                        XF[2*PSZ + orow*RS + oc] = (u16)(hb >> 16);
                        XF[3*PSZ + orow*RS + oc] = (u16)(lb >> 16);
                    }
                }
            } else {
                const int C = 1 << (s-7);     // 1,2,4
                const int w = wv - 8;
                if (w < 4) {
                    float4_t aP = z4, aN = z4, aI1 = z4, aI2 = z4;
                    cmm_ss<GSZ, PSZ, true>(Gm, XT, fm, w*16 + fm, fq, aP, aN, aI1, aI2);
#pragma unroll
                    for (int r = 0; r < 4; ++r) {
                        int orow = C + fq*4 + r;   // <= 19 < 32, no mask
                        int oc   = w*16 + fm;
                        unsigned hb, lb;
                        split2(aP[r] - aN[r], hb, lb);
                        Gm[orow*RS + oc]       = (u16)(hb >> 16);
                        Gm[GSZ + orow*RS + oc] = (u16)(lb >> 16);
                        split2(aI1[r] + aI2[r], hb, lb);
                        Gm[2*GSZ + orow*RS + oc] = (u16)(hb >> 16);
                        Gm[3*GSZ + orow*RS + oc] = (u16)(lb >> 16);
                    }
                }
            }
        } else if (wv < 4) {
            // squaring (waves 0-3, 32x32 tiles, 2-chain): P <- P*P
#pragma unroll
            for (int g = 0; g < 16; ++g) { sR[g] = 0.f; sI[g] = 0.f; }
            __builtin_amdgcn_s_setprio(1);   // T5: favor the long-pole MFMA waves
            cmm32_pk<PSZ>(XRrl, XRiI, XT, arow32, bcol32, khalf, sR, sI);
            __builtin_amdgcn_s_setprio(0);
        }
        __syncthreads();   // all P reads (riders + frags) complete
        if (wv < 4) {
            // store 32x32 C-frag into both views: XR b32 packed, XT b64
            const int col = tj2*32 + (lane & 31);
            const int hi4 = (lane >> 5) * 4;
#pragma unroll
            for (int q = 0; q < 4; ++q) {
                float r4[4], i4[4];
#pragma unroll
                for (int rr = 0; rr < 4; ++rr) { r4[rr] = sR[4*q+rr]; i4[rr] = sI[4*q+rr]; }
                const int rowb = ti2*32 + 8*q + hi4;
#pragma unroll
                for (int rr = 0; rr < 4; ++rr) {
                    XRrl[(rowb + rr)*RSW + col] = pack2(r4[rr]);
                    XRiI[(rowb + rr)*RSW + col] = pack2(i4[rr]);
                }
                store_XT16(XT, rowb, col, r4, i4);
            }
        }
        __syncthreads();
    }
    // P = dA^512 ; XF rows 0..63 = x_i ; Gm rows 0..7 = g_0..g_7

    // ---- tail tt = 0..3: chained dA^512 G-steps + K tiles (direct global) ----
    // G rows [8+8tt, 24+8tt) <- A rows [8tt, 8tt+16) (out row 8+ab+m depends
    // only on A row ab+m, so in-interval row overlap is benign).
#pragma unroll 1
    for (int tt = 0; tt < 4; ++tt) {
        if (tt < 3 && wv < 4) {
            const int ab = tt * 8;
            float4_t aP = z4, aN = z4, aI1 = z4, aI2 = z4;
            cmm_ss<GSZ, PSZ, true>(Gm, XT, ab + fm, wv*16 + fm, fq, aP, aN, aI1, aI2);
#pragma unroll
            for (int r = 0; r < 4; ++r) {
                int orow = 8 + ab + fq*4 + r;
                if (orow < 32) {
                    int oc = wv*16 + fm;
                    unsigned hb, lb;
                    split2(aP[r] - aN[r], hb, lb);
                    Gm[orow*RS + oc]       = (u16)(hb >> 16);
                    Gm[GSZ + orow*RS + oc] = (u16)(lb >> 16);
                    split2(aI1[r] + aI2[r], hb, lb);
                    Gm[2*GSZ + orow*RS + oc] = (u16)(hb >> 16);
                    Gm[3*GSZ + orow*RS + oc] = (u16)(lb >> 16);
                }
            }
        }
        if (wv >= 4 && wv < 8) {           // K rows [8tt, 8tt+8): direct global store
            const int jb = tt * 8;
            // clamp A row inside Gm's 32 rows (rows >= 32 feed only discarded C rows)
            int ga = jb + fm; if (ga > 31) ga = 31;
            float4_t aP = z4, aN = z4, aI1 = z4, aI2 = z4;
            __builtin_amdgcn_s_setprio(1);
            cmm_ss<GSZ, PSZ, false>(Gm, XF, ga, (wv-4)*16 + fm, fq, aP, aN, aI1, aI2);
            __builtin_amdgcn_s_setprio(0);
            if (fq < 2) {
                size_t base = (size_t)h * LSEQ;
#pragma unroll
                for (int r = 0; r < 4; ++r)
                    outp[base + (jb + fq*4 + r)*NN + (wv-4)*16 + fm] = aP[r] - aN[r];
            }
        }
        if (tt < 3) __syncthreads();
    }
}

extern "C" void kernel_launch(void* const* d_in, const int* in_sizes, int n_in,
                              void* d_out, int out_size, void* d_ws, size_t ws_size,
                              hipStream_t stream) {
    const float* A  = (const float*)d_in[0];
    const float* B  = (const float*)d_in[1];
    const float* C  = (const float*)d_in[2];
    const float* ld = (const float*)d_in[3];
    float* out = (float*)d_out;
    ssm_kernel<<<dim3(NH), dim3(NTH), 0, stream>>>(A, B, C, ld, out);
}